// Round 1
// baseline (1725.989 us; speedup 1.0000x reference)
//
#include <hip/hip_runtime.h>
#include <hip/hip_bf16.h>

// GraphTransformerLayer on MI355X.
// N=40000 nodes, E=640000 edges, D=128, H=8 heads, HD=16.
// Strategy: bf16 MFMA (16x16x32) for all GEMMs, f32 accumulate; e-path fully
// fused (e_out / e1 never hit HBM); edge->node reduction via f32 atomics.

constexpr int N_ = 40000;
constexpr int E_ = 640000;

typedef __attribute__((ext_vector_type(8))) short bf16x8;
typedef __attribute__((ext_vector_type(4))) float f32x4;

__device__ inline short f2bf(float f) {
    union { float f; unsigned u; } v; v.f = f;
    unsigned r = v.u + 0x7FFFu + ((v.u >> 16) & 1u);   // RNE
    return (short)(r >> 16);
}

__device__ inline f32x4 mfma16(bf16x8 a, bf16x8 b, f32x4 c) {
    return __builtin_amdgcn_mfma_f32_16x16x32_bf16(a, b, c, 0, 0, 0);
}

// Sum across the 16 lanes of a quarter-wave (lane bits 0..3).
__device__ inline float red16(float v) {
    v += __shfl_xor(v, 1);
    v += __shfl_xor(v, 2);
    v += __shfl_xor(v, 4);
    v += __shfl_xor(v, 8);
    return v;
}

// Load A-fragments (KSTEPS k-steps of 32) for MFMA from an LDS tile with
// row stride LDA (shorts). Row = rowB + (lane&15), k = ks*32 + (lane>>4)*8.
template<int KSTEPS, int LDA>
__device__ inline void load_af(const short* sA, int row, int g, bf16x8* af) {
#pragma unroll
    for (int ks = 0; ks < KSTEPS; ++ks)
        af[ks] = *(const bf16x8*)(sA + row * LDA + ks * 32 + g * 8);
}

// One 16-wide N-tile of a GEMM: acc = sum_ks A(ks) * B(ks).
// BtRow = Bt + (n*16+c)*Kin + g*8 ; Bt is bf16 [Nout][Kin] (transposed weight).
template<int KSTEPS>
__device__ inline f32x4 gemm_tile(const bf16x8* af, const short* BtRow) {
    f32x4 acc = {0.f, 0.f, 0.f, 0.f};
#pragma unroll
    for (int ks = 0; ks < KSTEPS; ++ks)
        acc = mfma16(af[ks], *(const bf16x8*)(BtRow + ks * 32), acc);
    return acc;
}

// Stage 16 rows (this wave's) of a [*,128] f32 matrix into LDS as bf16,
// row stride 136 shorts. Each lane: row rowB+(lane>>2), 32 cols.
__device__ inline void stage64(const float* __restrict__ gsrc, short* sA,
                               int lane, int rowB) {
    int rr = rowB + (lane >> 2);
    int c0 = (lane & 3) * 32;
    const float* gp = gsrc + (size_t)rr * 128 + c0;
    short* dp = sA + rr * 136 + c0;
#pragma unroll
    for (int p = 0; p < 4; ++p) {
        float4 x = *(const float4*)(gp + p * 8);
        float4 y = *(const float4*)(gp + p * 8 + 4);
        bf16x8 v;
        v[0] = f2bf(x.x); v[1] = f2bf(x.y); v[2] = f2bf(x.z); v[3] = f2bf(x.w);
        v[4] = f2bf(y.x); v[5] = f2bf(y.y); v[6] = f2bf(y.z); v[7] = f2bf(y.w);
        *(bf16x8*)(dp + p * 8) = v;
    }
}

// ---------------------------------------------------------------- prep
// Transpose + cast weights to bf16 [Nout][Kin].
// Layout in out: WQt,WKt,WVt,Wet,WOht,WOet (16384 each), then
// Wh1t, Wh2t, We1t, We2t (32768 each).
__global__ void prep_weights(
    const float* __restrict__ WQ, const float* __restrict__ WK,
    const float* __restrict__ WV, const float* __restrict__ We,
    const float* __restrict__ WOh, const float* __restrict__ WOe,
    const float* __restrict__ Wh1, const float* __restrict__ Wh2,
    const float* __restrict__ We1, const float* __restrict__ We2,
    short* __restrict__ out) {
    int i = blockIdx.x * 256 + threadIdx.x;
    if (i < 98304) {
        int m = i >> 14, j = i & 16383;
        int n = j >> 7, k = j & 127;
        const float* W = m == 0 ? WQ : m == 1 ? WK : m == 2 ? WV
                        : m == 3 ? We : m == 4 ? WOh : WOe;
        out[i] = f2bf(W[k * 128 + n]);
    } else if (i < 229376) {
        int j = i - 98304;
        int m = j >> 15; j &= 32767;
        const float* W = m == 0 ? Wh1 : m == 1 ? Wh2 : m == 2 ? We1 : We2;
        int ks = (m == 0 || m == 2) ? 7 : 8;       // Kin = 128 or 256
        int n = j >> ks, k = j & ((1 << ks) - 1);
        int Nout = 32768 >> ks;
        out[i] = f2bf(W[k * Nout + n]);
    }
}

// ---------------------------------------------------------------- QKV
__global__ void __launch_bounds__(256) qkv_kernel(
    const float* __restrict__ h, const short* __restrict__ Wt3,
    float* __restrict__ Qo, float* __restrict__ Ko, float* __restrict__ Vo) {
    __shared__ __align__(16) short sA[64 * 136];
    const int tb = blockIdx.x * 64;
    const int lane = threadIdx.x & 63, wave = threadIdx.x >> 6;
    const int c = lane & 15, g = lane >> 4;
    const int rowB = wave * 16;

    stage64(h + (size_t)tb * 128, sA, lane, rowB);
    __syncthreads();

    bf16x8 af[4];
    load_af<4, 136>(sA, rowB + c, g, af);

    float* outs[3] = {Qo, Ko, Vo};
#pragma unroll
    for (int w = 0; w < 3; ++w) {
        const short* Bt = Wt3 + w * 16384;
        float* op = outs[w];
#pragma unroll
        for (int n = 0; n < 8; ++n) {
            f32x4 a = gemm_tile<4>(af, Bt + (n * 16 + c) * 128 + g * 8);
            const int col = n * 16 + c;
#pragma unroll
            for (int r = 0; r < 4; ++r)
                op[(size_t)(tb + rowB + g * 4 + r) * 128 + col] = a[r];
        }
    }
}

// ---------------------------------------------------------------- edges
__global__ void __launch_bounds__(256) edge_kernel(
    const float* __restrict__ e, const int* __restrict__ src,
    const int* __restrict__ dst,
    const float* __restrict__ Q, const float* __restrict__ K,
    const float* __restrict__ V,
    float* __restrict__ wV, float* __restrict__ z,
    const short* __restrict__ Wet, const short* __restrict__ WOet,
    const short* __restrict__ We1t, const short* __restrict__ We2t,
    const float* __restrict__ bOe,
    const float* __restrict__ g1e, const float* __restrict__ b1e,
    const float* __restrict__ be1, const float* __restrict__ be2,
    const float* __restrict__ g2e, const float* __restrict__ b2e,
    float* __restrict__ e2out) {
    __shared__ __align__(16) short sA[64 * 136];
    __shared__ __align__(16) short sU[64 * 264];
    const int tb = blockIdx.x * 64;
    const int lane = threadIdx.x & 63, wave = threadIdx.x >> 6;
    const int c = lane & 15, g = lane >> 4;
    const int rowB = wave * 16;

    stage64(e + (size_t)tb * 128, sA, lane, rowB);
    __syncthreads();

    int sIdx[4], dIdx[4], mrow[4];
#pragma unroll
    for (int r = 0; r < 4; ++r) {
        mrow[r] = rowB + g * 4 + r;
        sIdx[r] = src[tb + mrow[r]];
        dIdx[r] = dst[tb + mrow[r]];
    }

    bf16x8 af[4];
    load_af<4, 136>(sA, rowB + c, g, af);

    // GEMM1: pe = e @ We   (acc layout: row = rowB+g*4+r, col = n*16+c; n==head)
    f32x4 pe[8];
#pragma unroll
    for (int n = 0; n < 8; ++n)
        pe[n] = gemm_tile<4>(af, Wet + (n * 16 + c) * 128 + g * 8);

    // score, exp, atomics, and score->bf16 back into sA (wave-private rows)
#pragma unroll
    for (int n = 0; n < 8; ++n) {
        const int col = n * 16 + c;
        float sc[4], se[4];
#pragma unroll
        for (int r = 0; r < 4; ++r) {
            float kv = K[(size_t)sIdx[r] * 128 + col];
            float qv = Q[(size_t)dIdx[r] * 128 + col];
            sc[r] = kv * qv * 0.25f * pe[n][r];
            float s = red16(sc[r]);
            s = fminf(5.f, fmaxf(-5.f, s));
            se[r] = expf(s);
        }
#pragma unroll
        for (int r = 0; r < 4; ++r) {
            float vv = V[(size_t)sIdx[r] * 128 + col];
            atomicAdd(&wV[(size_t)dIdx[r] * 128 + col], vv * se[r]);
            if (c == 0) atomicAdd(&z[(size_t)dIdx[r] * 8 + n], se[r]);
            sA[(rowB + g * 4 + r) * 136 + col] = f2bf(sc[r]);
        }
    }
    __syncthreads();

    // GEMM2: t = score @ WOe ; e1 = LN(e + t + bOe)
    load_af<4, 136>(sA, rowB + c, g, af);
    float x1[8][4];
    float sx[4] = {0, 0, 0, 0}, sxx[4] = {0, 0, 0, 0};
#pragma unroll
    for (int n = 0; n < 8; ++n) {
        f32x4 a2 = gemm_tile<4>(af, WOet + (n * 16 + c) * 128 + g * 8);
        const int col = n * 16 + c;
        float bo = bOe[col];
#pragma unroll
        for (int r = 0; r < 4; ++r) {
            float xv = a2[r] + bo + e[(size_t)(tb + mrow[r]) * 128 + col];
            x1[n][r] = xv; sx[r] += xv; sxx[r] += xv * xv;
        }
    }
    float mean[4], inv[4];
#pragma unroll
    for (int r = 0; r < 4; ++r) {
        float s = red16(sx[r]), s2 = red16(sxx[r]);
        mean[r] = s * 0.0078125f;
        float var = s2 * 0.0078125f - mean[r] * mean[r];
        inv[r] = rsqrtf(var + 1e-5f);
    }
#pragma unroll
    for (int n = 0; n < 8; ++n) {
        const int col = n * 16 + c;
        float gg = g1e[col], bb = b1e[col];
#pragma unroll
        for (int r = 0; r < 4; ++r) {
            float v1 = (x1[n][r] - mean[r]) * inv[r] * gg + bb;
            x1[n][r] = v1;
            sA[(rowB + g * 4 + r) * 136 + col] = f2bf(v1);
        }
    }
    __syncthreads();

    // GEMM3: u = relu(e1 @ We1 + be1) -> sU (bf16)
    load_af<4, 136>(sA, rowB + c, g, af);
#pragma unroll
    for (int n2 = 0; n2 < 16; ++n2) {
        f32x4 a3 = gemm_tile<4>(af, We1t + (n2 * 16 + c) * 128 + g * 8);
        const int col2 = n2 * 16 + c;
        float bb = be1[col2];
#pragma unroll
        for (int r = 0; r < 4; ++r)
            sU[(rowB + g * 4 + r) * 264 + col2] = f2bf(fmaxf(a3[r] + bb, 0.f));
    }
    __syncthreads();

    // GEMM4: v = u @ We2 + be2 ; e2 = LN(e1 + v)
    bf16x8 a4[8];
    load_af<8, 264>(sU, rowB + c, g, a4);
    float ty[4] = {0, 0, 0, 0}, tyy[4] = {0, 0, 0, 0};
#pragma unroll
    for (int n = 0; n < 8; ++n) {
        f32x4 a5 = gemm_tile<8>(a4, We2t + (n * 16 + c) * 256 + g * 8);
        const int col = n * 16 + c;
        float bb = be2[col];
#pragma unroll
        for (int r = 0; r < 4; ++r) {
            float xv = x1[n][r] + a5[r] + bb;
            x1[n][r] = xv; ty[r] += xv; tyy[r] += xv * xv;
        }
    }
#pragma unroll
    for (int r = 0; r < 4; ++r) {
        float s = red16(ty[r]), s2 = red16(tyy[r]);
        mean[r] = s * 0.0078125f;
        float var = s2 * 0.0078125f - mean[r] * mean[r];
        inv[r] = rsqrtf(var + 1e-5f);
    }
#pragma unroll
    for (int n = 0; n < 8; ++n) {
        const int col = n * 16 + c;
        float gg = g2e[col], bb = b2e[col];
#pragma unroll
        for (int r = 0; r < 4; ++r)
            e2out[(size_t)(tb + mrow[r]) * 128 + col] =
                (x1[n][r] - mean[r]) * inv[r] * gg + bb;
    }
}

// ---------------------------------------------------------------- nodes
__global__ void __launch_bounds__(256) node_kernel(
    const float* __restrict__ h, const float* __restrict__ wV,
    const float* __restrict__ z,
    const short* __restrict__ WOht, const short* __restrict__ Wh1t,
    const short* __restrict__ Wh2t,
    const float* __restrict__ bOh,
    const float* __restrict__ g1h, const float* __restrict__ b1h,
    const float* __restrict__ bh1, const float* __restrict__ bh2,
    const float* __restrict__ g2h, const float* __restrict__ b2h,
    float* __restrict__ h2out) {
    __shared__ __align__(16) short sA[64 * 136];
    __shared__ __align__(16) short sU[64 * 264];
    const int tb = blockIdx.x * 64;
    const int lane = threadIdx.x & 63, wave = threadIdx.x >> 6;
    const int c = lane & 15, g = lane >> 4;
    const int rowB = wave * 16;

    // stage h_attn = wV / (z + 1e-6) as bf16
    {
        int rr = rowB + (lane >> 2);
        size_t base = (size_t)(tb + rr) * 128;
        int c0 = (lane & 3) * 32;
#pragma unroll
        for (int p = 0; p < 4; ++p) {
            int cc = c0 + p * 8;
            float4 x = *(const float4*)(wV + base + cc);
            float4 y = *(const float4*)(wV + base + cc + 4);
            float iz = 1.f / (z[(tb + rr) * 8 + (cc >> 4)] + 1e-6f);
            bf16x8 v;
            v[0] = f2bf(x.x * iz); v[1] = f2bf(x.y * iz);
            v[2] = f2bf(x.z * iz); v[3] = f2bf(x.w * iz);
            v[4] = f2bf(y.x * iz); v[5] = f2bf(y.y * iz);
            v[6] = f2bf(y.z * iz); v[7] = f2bf(y.w * iz);
            *(bf16x8*)(sA + rr * 136 + cc) = v;
        }
    }
    __syncthreads();

    int mrow[4];
#pragma unroll
    for (int r = 0; r < 4; ++r) mrow[r] = rowB + g * 4 + r;

    // GEMM: t = h_attn @ WOh ; h1 = LN(h + t + bOh)
    bf16x8 af[4];
    load_af<4, 136>(sA, rowB + c, g, af);
    float x1[8][4];
    float sx[4] = {0, 0, 0, 0}, sxx[4] = {0, 0, 0, 0};
#pragma unroll
    for (int n = 0; n < 8; ++n) {
        f32x4 a2 = gemm_tile<4>(af, WOht + (n * 16 + c) * 128 + g * 8);
        const int col = n * 16 + c;
        float bo = bOh[col];
#pragma unroll
        for (int r = 0; r < 4; ++r) {
            float xv = a2[r] + bo + h[(size_t)(tb + mrow[r]) * 128 + col];
            x1[n][r] = xv; sx[r] += xv; sxx[r] += xv * xv;
        }
    }
    float mean[4], inv[4];
#pragma unroll
    for (int r = 0; r < 4; ++r) {
        float s = red16(sx[r]), s2 = red16(sxx[r]);
        mean[r] = s * 0.0078125f;
        float var = s2 * 0.0078125f - mean[r] * mean[r];
        inv[r] = rsqrtf(var + 1e-5f);
    }
#pragma unroll
    for (int n = 0; n < 8; ++n) {
        const int col = n * 16 + c;
        float gg = g1h[col], bb = b1h[col];
#pragma unroll
        for (int r = 0; r < 4; ++r) {
            float v1 = (x1[n][r] - mean[r]) * inv[r] * gg + bb;
            x1[n][r] = v1;
            sA[(rowB + g * 4 + r) * 136 + col] = f2bf(v1);
        }
    }
    __syncthreads();

    load_af<4, 136>(sA, rowB + c, g, af);
#pragma unroll
    for (int n2 = 0; n2 < 16; ++n2) {
        f32x4 a3 = gemm_tile<4>(af, Wh1t + (n2 * 16 + c) * 128 + g * 8);
        const int col2 = n2 * 16 + c;
        float bb = bh1[col2];
#pragma unroll
        for (int r = 0; r < 4; ++r)
            sU[(rowB + g * 4 + r) * 264 + col2] = f2bf(fmaxf(a3[r] + bb, 0.f));
    }
    __syncthreads();

    bf16x8 a4[8];
    load_af<8, 264>(sU, rowB + c, g, a4);
    float ty[4] = {0, 0, 0, 0}, tyy[4] = {0, 0, 0, 0};
#pragma unroll
    for (int n = 0; n < 8; ++n) {
        f32x4 a5 = gemm_tile<8>(a4, Wh2t + (n * 16 + c) * 256 + g * 8);
        const int col = n * 16 + c;
        float bb = bh2[col];
#pragma unroll
        for (int r = 0; r < 4; ++r) {
            float xv = x1[n][r] + a5[r] + bb;
            x1[n][r] = xv; ty[r] += xv; tyy[r] += xv * xv;
        }
    }
#pragma unroll
    for (int r = 0; r < 4; ++r) {
        float s = red16(ty[r]), s2 = red16(tyy[r]);
        mean[r] = s * 0.0078125f;
        float var = s2 * 0.0078125f - mean[r] * mean[r];
        inv[r] = rsqrtf(var + 1e-5f);
    }
#pragma unroll
    for (int n = 0; n < 8; ++n) {
        const int col = n * 16 + c;
        float gg = g2h[col], bb = b2h[col];
#pragma unroll
        for (int r = 0; r < 4; ++r)
            h2out[(size_t)(tb + mrow[r]) * 128 + col] =
                (x1[n][r] - mean[r]) * inv[r] * gg + bb;
    }
}

// ---------------------------------------------------------------- launch
extern "C" void kernel_launch(void* const* d_in, const int* in_sizes, int n_in,
                              void* d_out, int out_size, void* d_ws,
                              size_t ws_size, hipStream_t stream) {
    const float* h   = (const float*)d_in[0];
    const float* e   = (const float*)d_in[1];
    const int*   src = (const int*)d_in[2];
    const int*   dst = (const int*)d_in[3];
    const float* WQ  = (const float*)d_in[4];
    const float* WK  = (const float*)d_in[5];
    const float* WV  = (const float*)d_in[6];
    const float* We  = (const float*)d_in[7];
    const float* WOh = (const float*)d_in[8];
    const float* bOh = (const float*)d_in[9];
    const float* WOe = (const float*)d_in[10];
    const float* bOe = (const float*)d_in[11];
    const float* g1h = (const float*)d_in[12];
    const float* b1h = (const float*)d_in[13];
    const float* g1e = (const float*)d_in[14];
    const float* b1e = (const float*)d_in[15];
    const float* Wh1 = (const float*)d_in[16];
    const float* bh1 = (const float*)d_in[17];
    const float* Wh2 = (const float*)d_in[18];
    const float* bh2 = (const float*)d_in[19];
    const float* We1 = (const float*)d_in[20];
    const float* be1 = (const float*)d_in[21];
    const float* We2 = (const float*)d_in[22];
    const float* be2 = (const float*)d_in[23];
    const float* g2h = (const float*)d_in[24];
    const float* b2h = (const float*)d_in[25];
    const float* g2e = (const float*)d_in[26];
    const float* b2e = (const float*)d_in[27];

    float* Qw = (float*)d_ws;
    float* Kw = Qw + (size_t)N_ * 128;
    float* Vw = Kw + (size_t)N_ * 128;
    float* wV = Vw + (size_t)N_ * 128;
    float* zw = wV + (size_t)N_ * 128;
    short* Wb = (short*)(zw + (size_t)N_ * 8);

    float* h2out = (float*)d_out;
    float* e2out = h2out + (size_t)N_ * 128;

    prep_weights<<<896, 256, 0, stream>>>(WQ, WK, WV, We, WOh, WOe,
                                          Wh1, Wh2, We1, We2, Wb);
    hipMemsetAsync(wV, 0, ((size_t)N_ * 128 + (size_t)N_ * 8) * sizeof(float),
                   stream);
    qkv_kernel<<<N_ / 64, 256, 0, stream>>>(h, Wb, Qw, Kw, Vw);
    edge_kernel<<<E_ / 64, 256, 0, stream>>>(
        e, src, dst, Qw, Kw, Vw, wV, zw,
        Wb + 3 * 16384, Wb + 5 * 16384,
        Wb + 98304 + 2 * 32768, Wb + 98304 + 3 * 32768,
        bOe, g1e, b1e, be1, be2, g2e, b2e, e2out);
    node_kernel<<<N_ / 64, 256, 0, stream>>>(
        h, wV, zw, Wb + 4 * 16384, Wb + 98304, Wb + 98304 + 32768,
        bOh, g1h, b1h, bh1, bh2, g2h, b2h, h2out);
}

// Round 2
// 1598.463 us; speedup vs baseline: 1.0798x; 1.0798x over previous
//
#include <hip/hip_runtime.h>
#include <hip/hip_bf16.h>

// GraphTransformerLayer on MI355X — round 2.
// Changes vs round 1:
//  - CSR-by-dst pull reduction: no wV/z atomics (was 87M f32 memory-side RMWs).
//  - Edge kernel LDS 51KB -> 17.4KB (FFN in two 128-col halves reusing sA);
//    all LDS staging is wave-private 16-row bands -> no barriers at all.
//  - Q/K/V stored bf16; score phase gathers one 256B row per inst (2 cols/lane).

constexpr int N_ = 40000;
constexpr int E_ = 640000;

typedef __attribute__((ext_vector_type(8))) short bf16x8;
typedef __attribute__((ext_vector_type(4))) float f32x4;

__device__ inline short f2bf(float f) {
    union { float f; unsigned u; } v; v.f = f;
    unsigned r = v.u + 0x7FFFu + ((v.u >> 16) & 1u);   // RNE
    return (short)(r >> 16);
}
__device__ inline float bf2f(unsigned short u) {
    union { unsigned u; float f; } v; v.u = ((unsigned)u) << 16; return v.f;
}
__device__ inline unsigned packbf2(float a, float b) {
    return (unsigned)(unsigned short)f2bf(a) |
           ((unsigned)(unsigned short)f2bf(b) << 16);
}

__device__ inline f32x4 mfma16(bf16x8 a, bf16x8 b, f32x4 c) {
    return __builtin_amdgcn_mfma_f32_16x16x32_bf16(a, b, c, 0, 0, 0);
}

__device__ inline float red16(float v) {
    v += __shfl_xor(v, 1);
    v += __shfl_xor(v, 2);
    v += __shfl_xor(v, 4);
    v += __shfl_xor(v, 8);
    return v;
}

template<int KSTEPS, int LDA>
__device__ inline void load_af(const short* sA, int row, int g, bf16x8* af) {
#pragma unroll
    for (int ks = 0; ks < KSTEPS; ++ks)
        af[ks] = *(const bf16x8*)(sA + row * LDA + ks * 32 + g * 8);
}

template<int KSTEPS>
__device__ inline f32x4 gemm_tile(const bf16x8* af, const short* BtRow) {
    f32x4 acc = {0.f, 0.f, 0.f, 0.f};
#pragma unroll
    for (int ks = 0; ks < KSTEPS; ++ks)
        acc = mfma16(af[ks], *(const bf16x8*)(BtRow + ks * 32), acc);
    return acc;
}

// Stage this wave's 16 rows of a [*,128] f32 matrix into LDS as bf16 (wave-private).
__device__ inline void stage64(const float* __restrict__ gsrc, short* sA,
                               int lane, int rowB) {
    int rr = rowB + (lane >> 2);
    int c0 = (lane & 3) * 32;
    const float* gp = gsrc + (size_t)rr * 128 + c0;
    short* dp = sA + rr * 136 + c0;
#pragma unroll
    for (int p = 0; p < 4; ++p) {
        float4 x = *(const float4*)(gp + p * 8);
        float4 y = *(const float4*)(gp + p * 8 + 4);
        bf16x8 v;
        v[0] = f2bf(x.x); v[1] = f2bf(x.y); v[2] = f2bf(x.z); v[3] = f2bf(x.w);
        v[4] = f2bf(y.x); v[5] = f2bf(y.y); v[6] = f2bf(y.z); v[7] = f2bf(y.w);
        *(bf16x8*)(dp + p * 8) = v;
    }
}

// x1 = LN(resid + A@Bt + bias); A staged bf16 in sA; writes x1 bf16 back to sA.
__device__ inline void proj_ln(short* sA, const float* __restrict__ resid,
                               int tb, const short* __restrict__ Bt,
                               const float* __restrict__ bias,
                               const float* __restrict__ gma,
                               const float* __restrict__ beta,
                               int rowB, int c, int g, f32x4* x1v) {
    bf16x8 af[4];
    load_af<4, 136>(sA, rowB + c, g, af);
    float sx[4] = {0, 0, 0, 0}, sxx[4] = {0, 0, 0, 0};
#pragma unroll
    for (int n = 0; n < 8; ++n) {
        f32x4 a = gemm_tile<4>(af, Bt + (n * 16 + c) * 128 + g * 8);
        const int col = n * 16 + c;
        float bo = bias[col];
#pragma unroll
        for (int r = 0; r < 4; ++r) {
            float xv = a[r] + bo + resid[(size_t)(tb + rowB + g * 4 + r) * 128 + col];
            a[r] = xv; sx[r] += xv; sxx[r] += xv * xv;
        }
        x1v[n] = a;
    }
    float mean[4], inv[4];
#pragma unroll
    for (int r = 0; r < 4; ++r) {
        float s = red16(sx[r]), s2 = red16(sxx[r]);
        mean[r] = s * 0.0078125f;
        float var = s2 * 0.0078125f - mean[r] * mean[r];
        inv[r] = rsqrtf(var + 1e-5f);
    }
#pragma unroll
    for (int n = 0; n < 8; ++n) {
        const int col = n * 16 + c;
        float gg = gma[col], bb = beta[col];
#pragma unroll
        for (int r = 0; r < 4; ++r) {
            float v1 = (x1v[n][r] - mean[r]) * inv[r] * gg + bb;
            x1v[n][r] = v1;
            sA[(rowB + g * 4 + r) * 136 + col] = f2bf(v1);
        }
    }
}

// out = LN(x1 + relu(x1s@W1t + b1)@W2t + b2); x1 staged bf16 in sA (from proj_ln),
// x1v holds it in f32. FFN runs in two 128-col halves reusing sA.
__device__ inline void ffn_ln(short* sA, const short* __restrict__ W1t,
                              const float* __restrict__ b1,
                              const short* __restrict__ W2t,
                              const float* __restrict__ b2,
                              const float* __restrict__ gma,
                              const float* __restrict__ beta,
                              int rowB, int c, int g, f32x4* x1v,
                              float* __restrict__ outp, int tb) {
    bf16x8 af[4];
    load_af<4, 136>(sA, rowB + c, g, af);          // x1 fragments (held in regs)
#pragma unroll
    for (int half = 0; half < 2; ++half) {
#pragma unroll
        for (int n2 = 0; n2 < 8; ++n2) {
            f32x4 a3 = gemm_tile<4>(af, W1t + ((half * 8 + n2) * 16 + c) * 128 + g * 8);
            const int col2 = (half * 8 + n2) * 16 + c;
            float bb = b1[col2];
#pragma unroll
            for (int r = 0; r < 4; ++r)
                sA[(rowB + g * 4 + r) * 136 + n2 * 16 + c] =
                    f2bf(fmaxf(a3[r] + bb, 0.f));
        }
        bf16x8 a4[4];
        load_af<4, 136>(sA, rowB + c, g, a4);
#pragma unroll
        for (int n = 0; n < 8; ++n) {
            f32x4 acc = x1v[n];
#pragma unroll
            for (int ks = 0; ks < 4; ++ks)
                acc = mfma16(a4[ks],
                             *(const bf16x8*)(W2t + (n * 16 + c) * 256 +
                                              half * 128 + ks * 32 + g * 8),
                             acc);
            x1v[n] = acc;
        }
    }
    float ty[4] = {0, 0, 0, 0}, tyy[4] = {0, 0, 0, 0};
#pragma unroll
    for (int n = 0; n < 8; ++n) {
        const int col = n * 16 + c;
        float bb = b2[col];
#pragma unroll
        for (int r = 0; r < 4; ++r) {
            float xv = x1v[n][r] + bb;
            x1v[n][r] = xv; ty[r] += xv; tyy[r] += xv * xv;
        }
    }
    float mean[4], inv[4];
#pragma unroll
    for (int r = 0; r < 4; ++r) {
        float s = red16(ty[r]), s2 = red16(tyy[r]);
        mean[r] = s * 0.0078125f;
        float var = s2 * 0.0078125f - mean[r] * mean[r];
        inv[r] = rsqrtf(var + 1e-5f);
    }
#pragma unroll
    for (int n = 0; n < 8; ++n) {
        const int col = n * 16 + c;
        float gg = gma[col], bb = beta[col];
#pragma unroll
        for (int r = 0; r < 4; ++r)
            outp[(size_t)(tb + rowB + g * 4 + r) * 128 + col] =
                (x1v[n][r] - mean[r]) * inv[r] * gg + bb;
    }
}

// ---------------------------------------------------------------- prep
__global__ void prep_weights(
    const float* __restrict__ WQ, const float* __restrict__ WK,
    const float* __restrict__ WV, const float* __restrict__ We,
    const float* __restrict__ WOh, const float* __restrict__ WOe,
    const float* __restrict__ Wh1, const float* __restrict__ Wh2,
    const float* __restrict__ We1, const float* __restrict__ We2,
    short* __restrict__ out) {
    int i = blockIdx.x * 256 + threadIdx.x;
    if (i < 98304) {
        int m = i >> 14, j = i & 16383;
        int n = j >> 7, k = j & 127;
        const float* W = m == 0 ? WQ : m == 1 ? WK : m == 2 ? WV
                        : m == 3 ? We : m == 4 ? WOh : WOe;
        out[i] = f2bf(W[k * 128 + n]);
    } else if (i < 229376) {
        int j = i - 98304;
        int m = j >> 15; j &= 32767;
        const float* W = m == 0 ? Wh1 : m == 1 ? Wh2 : m == 2 ? We1 : We2;
        int ks = (m == 0 || m == 2) ? 7 : 8;       // Kin = 128 or 256
        int n = j >> ks, k = j & ((1 << ks) - 1);
        int Nout = 32768 >> ks;
        out[i] = f2bf(W[k * Nout + n]);
    }
}

// ---------------------------------------------------------------- CSR build
__global__ void hist_kernel(const int* __restrict__ dst, int* __restrict__ cnt) {
    int i = blockIdx.x * 256 + threadIdx.x;
    if (i < E_) atomicAdd(&cnt[dst[i]], 1);
}

__global__ void __launch_bounds__(1024) scan_kernel(const int* __restrict__ cnt,
                                                    int* __restrict__ off) {
    __shared__ int part[1024];
    int t = threadIdx.x;
    int base = t * 40;
    int s = 0;
    if (base < N_) {
        int end = min(base + 40, N_);
        for (int i = base; i < end; ++i) s += cnt[i];
    }
    part[t] = s;
    __syncthreads();
    for (int d = 1; d < 1024; d <<= 1) {
        int v = (t >= d) ? part[t - d] : 0;
        __syncthreads();
        part[t] += v;
        __syncthreads();
    }
    int prefix = (t == 0) ? 0 : part[t - 1];
    if (base < N_) {
        int end = min(base + 40, N_);
        int run = prefix;
        for (int i = base; i < end; ++i) { off[i] = run; run += cnt[i]; }
    }
    if (t == 1023) off[N_] = part[1023];
}

__global__ void scatter_kernel(const int* __restrict__ src,
                               const int* __restrict__ dst,
                               const int* __restrict__ off,
                               int* __restrict__ cursor,
                               int* __restrict__ slotOf,
                               int* __restrict__ csr_src) {
    int i = blockIdx.x * 256 + threadIdx.x;
    if (i < E_) {
        int d = dst[i];
        int s = off[d] + atomicAdd(&cursor[d], 1);
        slotOf[i] = s;
        csr_src[s] = src[i];
    }
}

// ---------------------------------------------------------------- QKV (bf16 out)
__global__ void __launch_bounds__(256) qkv_kernel(
    const float* __restrict__ hsrc, const short* __restrict__ Wt3,
    unsigned short* __restrict__ Qo, unsigned short* __restrict__ Ko,
    unsigned short* __restrict__ Vo) {
    __shared__ __align__(16) short sA[64 * 136];
    const int tb = blockIdx.x * 64;
    const int lane = threadIdx.x & 63, wave = threadIdx.x >> 6;
    const int c = lane & 15, g = lane >> 4;
    const int rowB = wave * 16;

    stage64(hsrc + (size_t)tb * 128, sA, lane, rowB);

    bf16x8 af[4];
    load_af<4, 136>(sA, rowB + c, g, af);

    unsigned short* outs[3] = {Qo, Ko, Vo};
#pragma unroll
    for (int w = 0; w < 3; ++w) {
        const short* Bt = Wt3 + w * 16384;
        unsigned short* op = outs[w];
#pragma unroll
        for (int n = 0; n < 8; ++n) {
            f32x4 a = gemm_tile<4>(af, Bt + (n * 16 + c) * 128 + g * 8);
            const int col = n * 16 + c;
#pragma unroll
            for (int r = 0; r < 4; ++r)
                op[(size_t)(tb + rowB + g * 4 + r) * 128 + col] =
                    (unsigned short)f2bf(a[r]);
        }
    }
}

// ---------------------------------------------------------------- edges
__global__ void __launch_bounds__(256) edge_kernel(
    const float* __restrict__ e, const int* __restrict__ src,
    const int* __restrict__ dst, const int* __restrict__ slotOf,
    const unsigned short* __restrict__ Qb, const unsigned short* __restrict__ Kb,
    float* __restrict__ sexpS,
    const short* __restrict__ Wet, const short* __restrict__ WOet,
    const short* __restrict__ We1t, const short* __restrict__ We2t,
    const float* __restrict__ bOe,
    const float* __restrict__ g1e, const float* __restrict__ b1e,
    const float* __restrict__ be1, const float* __restrict__ be2,
    const float* __restrict__ g2e, const float* __restrict__ b2e,
    float* __restrict__ e2out) {
    __shared__ __align__(16) short sA[64 * 136];
    const int tb = blockIdx.x * 64;
    const int lane = threadIdx.x & 63, wave = threadIdx.x >> 6;
    const int c = lane & 15, g = lane >> 4;
    const int rowB = wave * 16;

    stage64(e + (size_t)tb * 128, sA, lane, rowB);

    // GEMM1: pe = e @ We (fragments from sA, wave-private)
    bf16x8 af[4];
    load_af<4, 136>(sA, rowB + c, g, af);
    f32x4 pe[8];
#pragma unroll
    for (int n = 0; n < 8; ++n)
        pe[n] = gemm_tile<4>(af, Wet + (n * 16 + c) * 128 + g * 8);
    // stash pe bf16 in sA (overwrites staged e; residual re-reads global e)
#pragma unroll
    for (int n = 0; n < 8; ++n)
#pragma unroll
        for (int r = 0; r < 4; ++r)
            sA[(rowB + g * 4 + r) * 136 + n * 16 + c] = f2bf(pe[n][r]);

    // ---- score phase: 16 edges/wave, 2 cols per lane, one 256B gather per row
    const int head = lane >> 3;
#pragma unroll 4
    for (int i = 0; i < 16; ++i) {
        const int row = rowB + i;
        const int eidx = tb + row;
        const int sI = src[eidx], dI = dst[eidx];
        unsigned kk = *(const unsigned*)(Kb + (size_t)sI * 128 + 2 * lane);
        unsigned qq = *(const unsigned*)(Qb + (size_t)dI * 128 + 2 * lane);
        unsigned pp = *(const unsigned*)(sA + row * 136 + 2 * lane);
        float sc0 = bf2f((unsigned short)kk) * bf2f((unsigned short)qq) * 0.25f *
                    bf2f((unsigned short)pp);
        float sc1 = bf2f((unsigned short)(kk >> 16)) *
                    bf2f((unsigned short)(qq >> 16)) * 0.25f *
                    bf2f((unsigned short)(pp >> 16));
        *(unsigned*)(sA + row * 136 + 2 * lane) = packbf2(sc0, sc1);
        float s = sc0 + sc1;
        s += __shfl_xor(s, 1);
        s += __shfl_xor(s, 2);
        s += __shfl_xor(s, 4);
        s = fminf(5.f, fmaxf(-5.f, s));
        if ((lane & 7) == 0)
            sexpS[(size_t)slotOf[eidx] * 8 + head] = expf(s);
    }

    // GEMM2 + LN1, then FFN + LN2 (all wave-private staging in sA)
    f32x4 x1v[8];
    proj_ln(sA, e, tb, WOet, bOe, g1e, b1e, rowB, c, g, x1v);
    ffn_ln(sA, We1t, be1, We2t, be2, g2e, b2e, rowB, c, g, x1v, e2out, tb);
}

// ---------------------------------------------------------------- nodes
__global__ void __launch_bounds__(256) node_kernel(
    const float* __restrict__ h, const unsigned short* __restrict__ Vb,
    const float* __restrict__ sexpS,
    const int* __restrict__ off, const int* __restrict__ csr_src,
    const short* __restrict__ WOht, const short* __restrict__ Wh1t,
    const short* __restrict__ Wh2t,
    const float* __restrict__ bOh,
    const float* __restrict__ g1h, const float* __restrict__ b1h,
    const float* __restrict__ bh1, const float* __restrict__ bh2,
    const float* __restrict__ g2h, const float* __restrict__ b2h,
    float* __restrict__ h2out) {
    __shared__ __align__(16) short sA[64 * 136];
    const int tb = blockIdx.x * 64;
    const int lane = threadIdx.x & 63, wave = threadIdx.x >> 6;
    const int c = lane & 15, g = lane >> 4;
    const int rowB = wave * 16;
    const int head = lane >> 3;

    // phase A: pull-reduce h_attn for this wave's 16 nodes (no atomics)
    for (int i = 0; i < 16; ++i) {
        const int node = tb + rowB + i;
        const int b0 = off[node], b1 = off[node + 1];
        float a0 = 0.f, a1 = 0.f, zz = 0.f;
        for (int j = b0; j < b1; ++j) {
            float s = sexpS[(size_t)j * 8 + head];
            unsigned vv = *(const unsigned*)(Vb + (size_t)csr_src[j] * 128 + 2 * lane);
            a0 += bf2f((unsigned short)vv) * s;
            a1 += bf2f((unsigned short)(vv >> 16)) * s;
            zz += s;
        }
        float iz = 1.f / (zz + 1e-6f);
        *(unsigned*)(sA + (rowB + i) * 136 + 2 * lane) = packbf2(a0 * iz, a1 * iz);
    }

    f32x4 x1v[8];
    proj_ln(sA, h, tb, WOht, bOh, g1h, b1h, rowB, c, g, x1v);
    ffn_ln(sA, Wh1t, bh1, Wh2t, bh2, g2h, b2h, rowB, c, g, x1v, h2out, tb);
}

// ---------------------------------------------------------------- launch
extern "C" void kernel_launch(void* const* d_in, const int* in_sizes, int n_in,
                              void* d_out, int out_size, void* d_ws,
                              size_t ws_size, hipStream_t stream) {
    const float* h   = (const float*)d_in[0];
    const float* e   = (const float*)d_in[1];
    const int*   src = (const int*)d_in[2];
    const int*   dst = (const int*)d_in[3];
    const float* WQ  = (const float*)d_in[4];
    const float* WK  = (const float*)d_in[5];
    const float* WV  = (const float*)d_in[6];
    const float* We  = (const float*)d_in[7];
    const float* WOh = (const float*)d_in[8];
    const float* bOh = (const float*)d_in[9];
    const float* WOe = (const float*)d_in[10];
    const float* bOe = (const float*)d_in[11];
    const float* g1h = (const float*)d_in[12];
    const float* b1h = (const float*)d_in[13];
    const float* g1e = (const float*)d_in[14];
    const float* b1e = (const float*)d_in[15];
    const float* Wh1 = (const float*)d_in[16];
    const float* bh1 = (const float*)d_in[17];
    const float* Wh2 = (const float*)d_in[18];
    const float* bh2 = (const float*)d_in[19];
    const float* We1 = (const float*)d_in[20];
    const float* be1 = (const float*)d_in[21];
    const float* We2 = (const float*)d_in[22];
    const float* be2 = (const float*)d_in[23];
    const float* g2h = (const float*)d_in[24];
    const float* b2h = (const float*)d_in[25];
    const float* g2e = (const float*)d_in[26];
    const float* b2e = (const float*)d_in[27];

    // workspace layout (~57.3 MB total)
    unsigned short* Qb = (unsigned short*)d_ws;            // N*128 bf16
    unsigned short* Kb = Qb + (size_t)N_ * 128;
    unsigned short* Vb = Kb + (size_t)N_ * 128;
    float* sexpS = (float*)(Vb + (size_t)N_ * 128);        // E*8 (CSR slot order)
    int* cnt     = (int*)(sexpS + (size_t)E_ * 8);         // N
    int* cursor  = cnt + N_;                               // N
    int* off     = cursor + N_;                            // N+1
    int* slotOf  = off + N_ + 1;                           // E
    int* csr_src = slotOf + E_;                            // E
    short* Wb    = (short*)(csr_src + E_);                 // bf16 weights

    float* h2out = (float*)d_out;
    float* e2out = h2out + (size_t)N_ * 128;

    prep_weights<<<896, 256, 0, stream>>>(WQ, WK, WV, We, WOh, WOe,
                                          Wh1, Wh2, We1, We2, Wb);
    hipMemsetAsync(cnt, 0, 2 * N_ * sizeof(int), stream);  // cnt + cursor
    hist_kernel<<<E_ / 256, 256, 0, stream>>>(dst, cnt);
    scan_kernel<<<1, 1024, 0, stream>>>(cnt, off);
    scatter_kernel<<<E_ / 256, 256, 0, stream>>>(src, dst, off, cursor,
                                                 slotOf, csr_src);
    qkv_kernel<<<N_ / 64, 256, 0, stream>>>(h, Wb, Qb, Kb, Vb);
    edge_kernel<<<E_ / 64, 256, 0, stream>>>(
        e, src, dst, slotOf, Qb, Kb, sexpS,
        Wb + 3 * 16384, Wb + 5 * 16384,
        Wb + 98304 + 2 * 32768, Wb + 98304 + 3 * 32768,
        bOe, g1e, b1e, be1, be2, g2e, b2e, e2out);
    node_kernel<<<N_ / 64, 256, 0, stream>>>(
        h, Vb, sexpS, off, csr_src,
        Wb + 4 * 16384, Wb + 98304, Wb + 98304 + 32768,
        bOh, g1h, b1h, bh1, bh2, g2h, b2h, h2out);
}

// Round 4
// 1245.241 us; speedup vs baseline: 1.3861x; 1.2837x over previous
//
#include <hip/hip_runtime.h>
#include <hip/hip_bf16.h>

// GraphTransformerLayer on MI355X — round 4 (= round 3 + shfl-divergence fix).
//  - score-phase gathers batched (preloaded indices + 8-wide register staging)
//  - residuals (e, h) stay staged in a second LDS buffer; no global re-read
//  - node CSR pull batched 8-wide with predicated gathers
//  - FIX: slot index __shfl hoisted out of the divergent store (inactive-lane
//    cross-lane reads are undefined -> round 3's h2 corruption).

constexpr int N_ = 40000;
constexpr int E_ = 640000;

typedef __attribute__((ext_vector_type(8))) short bf16x8;
typedef __attribute__((ext_vector_type(4))) float f32x4;

__device__ inline short f2bf(float f) {
    union { float f; unsigned u; } v; v.f = f;
    unsigned r = v.u + 0x7FFFu + ((v.u >> 16) & 1u);   // RNE
    return (short)(r >> 16);
}
__device__ inline float bf2f(unsigned short u) {
    union { unsigned u; float f; } v; v.u = ((unsigned)u) << 16; return v.f;
}
__device__ inline unsigned packbf2(float a, float b) {
    return (unsigned)(unsigned short)f2bf(a) |
           ((unsigned)(unsigned short)f2bf(b) << 16);
}

__device__ inline f32x4 mfma16(bf16x8 a, bf16x8 b, f32x4 c) {
    return __builtin_amdgcn_mfma_f32_16x16x32_bf16(a, b, c, 0, 0, 0);
}

__device__ inline float red16(float v) {
    v += __shfl_xor(v, 1);
    v += __shfl_xor(v, 2);
    v += __shfl_xor(v, 4);
    v += __shfl_xor(v, 8);
    return v;
}

template<int KSTEPS, int LDA>
__device__ inline void load_af(const short* sA, int row, int g, bf16x8* af) {
#pragma unroll
    for (int ks = 0; ks < KSTEPS; ++ks)
        af[ks] = *(const bf16x8*)(sA + row * LDA + ks * 32 + g * 8);
}

template<int KSTEPS>
__device__ inline f32x4 gemm_tile(const bf16x8* af, const short* BtRow) {
    f32x4 acc = {0.f, 0.f, 0.f, 0.f};
#pragma unroll
    for (int ks = 0; ks < KSTEPS; ++ks)
        acc = mfma16(af[ks], *(const bf16x8*)(BtRow + ks * 32), acc);
    return acc;
}

// Stage this wave's 16 rows of a [*,128] f32 matrix into LDS as bf16 (wave-private).
__device__ inline void stage64(const float* __restrict__ gsrc, short* sA,
                               int lane, int rowB) {
    int rr = rowB + (lane >> 2);
    int c0 = (lane & 3) * 32;
    const float* gp = gsrc + (size_t)rr * 128 + c0;
    short* dp = sA + rr * 136 + c0;
#pragma unroll
    for (int p = 0; p < 4; ++p) {
        float4 x = *(const float4*)(gp + p * 8);
        float4 y = *(const float4*)(gp + p * 8 + 4);
        bf16x8 v;
        v[0] = f2bf(x.x); v[1] = f2bf(x.y); v[2] = f2bf(x.z); v[3] = f2bf(x.w);
        v[4] = f2bf(y.x); v[5] = f2bf(y.y); v[6] = f2bf(y.z); v[7] = f2bf(y.w);
        *(bf16x8*)(dp + p * 8) = v;
    }
}

// x1 = LN(residLDS + A@Bt + bias); A staged bf16 in sA; writes x1 bf16 to sA.
__device__ inline void proj_ln(short* sA, const short* __restrict__ sE,
                               const short* __restrict__ Bt,
                               const float* __restrict__ bias,
                               const float* __restrict__ gma,
                               const float* __restrict__ beta,
                               int rowB, int c, int g, f32x4* x1v) {
    bf16x8 af[4];
    load_af<4, 136>(sA, rowB + c, g, af);
    float sx[4] = {0, 0, 0, 0}, sxx[4] = {0, 0, 0, 0};
#pragma unroll
    for (int n = 0; n < 8; ++n) {
        f32x4 a = gemm_tile<4>(af, Bt + (n * 16 + c) * 128 + g * 8);
        const int col = n * 16 + c;
        float bo = bias[col];
#pragma unroll
        for (int r = 0; r < 4; ++r) {
            float xv = a[r] + bo +
                       bf2f((unsigned short)sE[(rowB + g * 4 + r) * 136 + col]);
            a[r] = xv; sx[r] += xv; sxx[r] += xv * xv;
        }
        x1v[n] = a;
    }
    float mean[4], inv[4];
#pragma unroll
    for (int r = 0; r < 4; ++r) {
        float s = red16(sx[r]), s2 = red16(sxx[r]);
        mean[r] = s * 0.0078125f;
        float var = s2 * 0.0078125f - mean[r] * mean[r];
        inv[r] = rsqrtf(var + 1e-5f);
    }
#pragma unroll
    for (int n = 0; n < 8; ++n) {
        const int col = n * 16 + c;
        float gg = gma[col], bb = beta[col];
#pragma unroll
        for (int r = 0; r < 4; ++r) {
            float v1 = (x1v[n][r] - mean[r]) * inv[r] * gg + bb;
            x1v[n][r] = v1;
            sA[(rowB + g * 4 + r) * 136 + col] = f2bf(v1);
        }
    }
}

// out = LN(x1 + relu(x1@W1t + b1)@W2t + b2); x1 bf16 in sA, f32 in x1v.
__device__ inline void ffn_ln(short* sA, const short* __restrict__ W1t,
                              const float* __restrict__ b1,
                              const short* __restrict__ W2t,
                              const float* __restrict__ b2,
                              const float* __restrict__ gma,
                              const float* __restrict__ beta,
                              int rowB, int c, int g, f32x4* x1v,
                              float* __restrict__ outp, int tb) {
    bf16x8 af[4];
    load_af<4, 136>(sA, rowB + c, g, af);
#pragma unroll
    for (int half = 0; half < 2; ++half) {
#pragma unroll
        for (int n2 = 0; n2 < 8; ++n2) {
            f32x4 a3 = gemm_tile<4>(af, W1t + ((half * 8 + n2) * 16 + c) * 128 + g * 8);
            const int col2 = (half * 8 + n2) * 16 + c;
            float bb = b1[col2];
#pragma unroll
            for (int r = 0; r < 4; ++r)
                sA[(rowB + g * 4 + r) * 136 + n2 * 16 + c] =
                    f2bf(fmaxf(a3[r] + bb, 0.f));
        }
        bf16x8 a4[4];
        load_af<4, 136>(sA, rowB + c, g, a4);
#pragma unroll
        for (int n = 0; n < 8; ++n) {
            f32x4 acc = x1v[n];
#pragma unroll
            for (int ks = 0; ks < 4; ++ks)
                acc = mfma16(a4[ks],
                             *(const bf16x8*)(W2t + (n * 16 + c) * 256 +
                                              half * 128 + ks * 32 + g * 8),
                             acc);
            x1v[n] = acc;
        }
    }
    float ty[4] = {0, 0, 0, 0}, tyy[4] = {0, 0, 0, 0};
#pragma unroll
    for (int n = 0; n < 8; ++n) {
        const int col = n * 16 + c;
        float bb = b2[col];
#pragma unroll
        for (int r = 0; r < 4; ++r) {
            float xv = x1v[n][r] + bb;
            x1v[n][r] = xv; ty[r] += xv; tyy[r] += xv * xv;
        }
    }
    float mean[4], inv[4];
#pragma unroll
    for (int r = 0; r < 4; ++r) {
        float s = red16(ty[r]), s2 = red16(tyy[r]);
        mean[r] = s * 0.0078125f;
        float var = s2 * 0.0078125f - mean[r] * mean[r];
        inv[r] = rsqrtf(var + 1e-5f);
    }
#pragma unroll
    for (int n = 0; n < 8; ++n) {
        const int col = n * 16 + c;
        float gg = gma[col], bb = beta[col];
#pragma unroll
        for (int r = 0; r < 4; ++r)
            outp[(size_t)(tb + rowB + g * 4 + r) * 128 + col] =
                (x1v[n][r] - mean[r]) * inv[r] * gg + bb;
    }
}

// ---------------------------------------------------------------- prep
__global__ void prep_weights(
    const float* __restrict__ WQ, const float* __restrict__ WK,
    const float* __restrict__ WV, const float* __restrict__ We,
    const float* __restrict__ WOh, const float* __restrict__ WOe,
    const float* __restrict__ Wh1, const float* __restrict__ Wh2,
    const float* __restrict__ We1, const float* __restrict__ We2,
    short* __restrict__ out) {
    int i = blockIdx.x * 256 + threadIdx.x;
    if (i < 98304) {
        int m = i >> 14, j = i & 16383;
        int n = j >> 7, k = j & 127;
        const float* W = m == 0 ? WQ : m == 1 ? WK : m == 2 ? WV
                        : m == 3 ? We : m == 4 ? WOh : WOe;
        out[i] = f2bf(W[k * 128 + n]);
    } else if (i < 229376) {
        int j = i - 98304;
        int m = j >> 15; j &= 32767;
        const float* W = m == 0 ? Wh1 : m == 1 ? Wh2 : m == 2 ? We1 : We2;
        int ks = (m == 0 || m == 2) ? 7 : 8;       // Kin = 128 or 256
        int n = j >> ks, k = j & ((1 << ks) - 1);
        int Nout = 32768 >> ks;
        out[i] = f2bf(W[k * Nout + n]);
    }
}

// ---------------------------------------------------------------- CSR build
__global__ void hist_kernel(const int* __restrict__ dst, int* __restrict__ cnt) {
    int i = blockIdx.x * 256 + threadIdx.x;
    if (i < E_) atomicAdd(&cnt[dst[i]], 1);
}

__global__ void __launch_bounds__(1024) scan_kernel(const int* __restrict__ cnt,
                                                    int* __restrict__ off) {
    __shared__ int part[1024];
    int t = threadIdx.x;
    int base = t * 40;
    int s = 0;
    if (base < N_) {
        int end = min(base + 40, N_);
        for (int i = base; i < end; ++i) s += cnt[i];
    }
    part[t] = s;
    __syncthreads();
    for (int d = 1; d < 1024; d <<= 1) {
        int v = (t >= d) ? part[t - d] : 0;
        __syncthreads();
        part[t] += v;
        __syncthreads();
    }
    int prefix = (t == 0) ? 0 : part[t - 1];
    if (base < N_) {
        int end = min(base + 40, N_);
        int run = prefix;
        for (int i = base; i < end; ++i) { off[i] = run; run += cnt[i]; }
    }
    if (t == 1023) off[N_] = part[1023];
}

__global__ void scatter_kernel(const int* __restrict__ src,
                               const int* __restrict__ dst,
                               const int* __restrict__ off,
                               int* __restrict__ cursor,
                               int* __restrict__ slotOf,
                               int* __restrict__ csr_src) {
    int i = blockIdx.x * 256 + threadIdx.x;
    if (i < E_) {
        int d = dst[i];
        int s = off[d] + atomicAdd(&cursor[d], 1);
        slotOf[i] = s;
        csr_src[s] = src[i];
    }
}

// ---------------------------------------------------------------- QKV (bf16 out)
__global__ void __launch_bounds__(256) qkv_kernel(
    const float* __restrict__ hsrc, const short* __restrict__ Wt3,
    unsigned short* __restrict__ Qo, unsigned short* __restrict__ Ko,
    unsigned short* __restrict__ Vo) {
    __shared__ __align__(16) short sA[64 * 136];
    const int tb = blockIdx.x * 64;
    const int lane = threadIdx.x & 63, wave = threadIdx.x >> 6;
    const int c = lane & 15, g = lane >> 4;
    const int rowB = wave * 16;

    stage64(hsrc + (size_t)tb * 128, sA, lane, rowB);

    bf16x8 af[4];
    load_af<4, 136>(sA, rowB + c, g, af);

    unsigned short* outs[3] = {Qo, Ko, Vo};
#pragma unroll
    for (int w = 0; w < 3; ++w) {
        const short* Bt = Wt3 + w * 16384;
        unsigned short* op = outs[w];
#pragma unroll
        for (int n = 0; n < 8; ++n) {
            f32x4 a = gemm_tile<4>(af, Bt + (n * 16 + c) * 128 + g * 8);
            const int col = n * 16 + c;
#pragma unroll
            for (int r = 0; r < 4; ++r)
                op[(size_t)(tb + rowB + g * 4 + r) * 128 + col] =
                    (unsigned short)f2bf(a[r]);
        }
    }
}

// ---------------------------------------------------------------- edges
__global__ void __launch_bounds__(256) edge_kernel(
    const float* __restrict__ e, const int* __restrict__ src,
    const int* __restrict__ dst, const int* __restrict__ slotOf,
    const unsigned short* __restrict__ Qb, const unsigned short* __restrict__ Kb,
    float* __restrict__ sexpS,
    const short* __restrict__ Wet, const short* __restrict__ WOet,
    const short* __restrict__ We1t, const short* __restrict__ We2t,
    const float* __restrict__ bOe,
    const float* __restrict__ g1e, const float* __restrict__ b1e,
    const float* __restrict__ be1, const float* __restrict__ be2,
    const float* __restrict__ g2e, const float* __restrict__ b2e,
    float* __restrict__ e2out) {
    __shared__ __align__(16) short sE[64 * 136];   // staged e: GEMM1 A + residual
    __shared__ __align__(16) short sA[64 * 136];   // scratch: pe -> score -> x1 -> relu
    const int tb = blockIdx.x * 64;
    const int lane = threadIdx.x & 63, wave = threadIdx.x >> 6;
    const int c = lane & 15, g = lane >> 4;
    const int rowB = wave * 16;

    stage64(e + (size_t)tb * 128, sE, lane, rowB);

    // preload this wave's 16 src / 16 dst / 16 slot indices (lane-partitioned)
    int pre = 0;
    {
        int li = lane & 15;
        if (lane < 16)       pre = src[tb + rowB + li];
        else if (lane < 32)  pre = dst[tb + rowB + li];
        else if (lane < 48)  pre = slotOf[tb + rowB + li];
    }

    // GEMM1: pe = e @ We -> stash bf16 into sA
    bf16x8 af[4];
    load_af<4, 136>(sE, rowB + c, g, af);
#pragma unroll
    for (int n = 0; n < 8; ++n) {
        f32x4 p = gemm_tile<4>(af, Wet + (n * 16 + c) * 128 + g * 8);
#pragma unroll
        for (int r = 0; r < 4; ++r)
            sA[(rowB + g * 4 + r) * 136 + n * 16 + c] = f2bf(p[r]);
    }

    // ---- score phase: 2 batches of 8 edges; gathers issued 16-deep
    const int head = lane >> 3;
#pragma unroll
    for (int b = 0; b < 2; ++b) {
        unsigned kreg[8], qreg[8];
#pragma unroll
        for (int k = 0; k < 8; ++k) {
            int sI = __shfl(pre, b * 8 + k);
            kreg[k] = *(const unsigned*)(Kb + (size_t)sI * 128 + 2 * lane);
        }
#pragma unroll
        for (int k = 0; k < 8; ++k) {
            int dI = __shfl(pre, 16 + b * 8 + k);
            qreg[k] = *(const unsigned*)(Qb + (size_t)dI * 128 + 2 * lane);
        }
#pragma unroll
        for (int k = 0; k < 8; ++k) {
            const int i = b * 8 + k;
            const int row = rowB + i;
            // full-wave shfl (source lanes must be active: do it OUTSIDE the if)
            const int slot = __shfl(pre, 32 + i);
            unsigned pp = *(const unsigned*)(sA + row * 136 + 2 * lane);
            float sc0 = bf2f((unsigned short)kreg[k]) *
                        bf2f((unsigned short)qreg[k]) * 0.25f *
                        bf2f((unsigned short)pp);
            float sc1 = bf2f((unsigned short)(kreg[k] >> 16)) *
                        bf2f((unsigned short)(qreg[k] >> 16)) * 0.25f *
                        bf2f((unsigned short)(pp >> 16));
            *(unsigned*)(sA + row * 136 + 2 * lane) = packbf2(sc0, sc1);
            float s = sc0 + sc1;
            s += __shfl_xor(s, 1);
            s += __shfl_xor(s, 2);
            s += __shfl_xor(s, 4);
            s = fminf(5.f, fmaxf(-5.f, s));
            if ((lane & 7) == 0)
                sexpS[(size_t)slot * 8 + head] = __expf(s);
        }
    }

    // GEMM2 + LN1 (residual from sE), then FFN + LN2
    f32x4 x1v[8];
    proj_ln(sA, sE, WOet, bOe, g1e, b1e, rowB, c, g, x1v);
    ffn_ln(sA, We1t, be1, We2t, be2, g2e, b2e, rowB, c, g, x1v, e2out, tb);
}

// ---------------------------------------------------------------- nodes
__global__ void __launch_bounds__(256) node_kernel(
    const float* __restrict__ h, const unsigned short* __restrict__ Vb,
    const float* __restrict__ sexpS,
    const int* __restrict__ off, const int* __restrict__ csr_src,
    const short* __restrict__ WOht, const short* __restrict__ Wh1t,
    const short* __restrict__ Wh2t,
    const float* __restrict__ bOh,
    const float* __restrict__ g1h, const float* __restrict__ b1h,
    const float* __restrict__ bh1, const float* __restrict__ bh2,
    const float* __restrict__ g2h, const float* __restrict__ b2h,
    float* __restrict__ h2out) {
    __shared__ __align__(16) short sE[64 * 136];   // staged h (residual)
    __shared__ __align__(16) short sA[64 * 136];   // h_attn -> x1 -> relu
    const int tb = blockIdx.x * 64;
    const int lane = threadIdx.x & 63, wave = threadIdx.x >> 6;
    const int c = lane & 15, g = lane >> 4;
    const int rowB = wave * 16;
    const int head = lane >> 3;

    stage64(h + (size_t)tb * 128, sE, lane, rowB);

    // preload CSR offsets for this wave's 16 nodes (+1)
    int offv = (lane < 17) ? off[tb + rowB + lane] : 0;

    // phase A: pull-reduce h_attn, batched 8-wide
    for (int i = 0; i < 16; ++i) {
        const int b0 = __shfl(offv, i), b1 = __shfl(offv, i + 1);
        float a0 = 0.f, a1 = 0.f, zz = 0.f;
        for (int j0 = b0; j0 < b1; j0 += 8) {
            int jj = j0 + (lane & 7);
            int ci = (jj < b1) ? csr_src[jj] : 0;
            unsigned vv[8]; float sv[8];
#pragma unroll
            for (int k = 0; k < 8; ++k) {
                bool ok = (j0 + k) < b1;
                int cs = __shfl(ci, k);
                vv[k] = ok ? *(const unsigned*)(Vb + (size_t)cs * 128 + 2 * lane)
                           : 0u;
                sv[k] = ok ? sexpS[(size_t)(j0 + k) * 8 + head] : 0.f;
            }
#pragma unroll
            for (int k = 0; k < 8; ++k) {
                a0 += bf2f((unsigned short)vv[k]) * sv[k];
                a1 += bf2f((unsigned short)(vv[k] >> 16)) * sv[k];
                zz += sv[k];
            }
        }
        float iz = 1.f / (zz + 1e-6f);
        *(unsigned*)(sA + (rowB + i) * 136 + 2 * lane) = packbf2(a0 * iz, a1 * iz);
    }

    f32x4 x1v[8];
    proj_ln(sA, sE, WOht, bOh, g1h, b1h, rowB, c, g, x1v);
    ffn_ln(sA, Wh1t, bh1, Wh2t, bh2, g2h, b2h, rowB, c, g, x1v, h2out, tb);
}

// ---------------------------------------------------------------- launch
extern "C" void kernel_launch(void* const* d_in, const int* in_sizes, int n_in,
                              void* d_out, int out_size, void* d_ws,
                              size_t ws_size, hipStream_t stream) {
    const float* h   = (const float*)d_in[0];
    const float* e   = (const float*)d_in[1];
    const int*   src = (const int*)d_in[2];
    const int*   dst = (const int*)d_in[3];
    const float* WQ  = (const float*)d_in[4];
    const float* WK  = (const float*)d_in[5];
    const float* WV  = (const float*)d_in[6];
    const float* We  = (const float*)d_in[7];
    const float* WOh = (const float*)d_in[8];
    const float* bOh = (const float*)d_in[9];
    const float* WOe = (const float*)d_in[10];
    const float* bOe = (const float*)d_in[11];
    const float* g1h = (const float*)d_in[12];
    const float* b1h = (const float*)d_in[13];
    const float* g1e = (const float*)d_in[14];
    const float* b1e = (const float*)d_in[15];
    const float* Wh1 = (const float*)d_in[16];
    const float* bh1 = (const float*)d_in[17];
    const float* Wh2 = (const float*)d_in[18];
    const float* bh2 = (const float*)d_in[19];
    const float* We1 = (const float*)d_in[20];
    const float* be1 = (const float*)d_in[21];
    const float* We2 = (const float*)d_in[22];
    const float* be2 = (const float*)d_in[23];
    const float* g2h = (const float*)d_in[24];
    const float* b2h = (const float*)d_in[25];
    const float* g2e = (const float*)d_in[26];
    const float* b2e = (const float*)d_in[27];

    unsigned short* Qb = (unsigned short*)d_ws;            // N*128 bf16
    unsigned short* Kb = Qb + (size_t)N_ * 128;
    unsigned short* Vb = Kb + (size_t)N_ * 128;
    float* sexpS = (float*)(Vb + (size_t)N_ * 128);        // E*8 (CSR slot order)
    int* cnt     = (int*)(sexpS + (size_t)E_ * 8);         // N
    int* cursor  = cnt + N_;                               // N
    int* off     = cursor + N_;                            // N+1
    int* slotOf  = off + N_ + 1;                           // E
    int* csr_src = slotOf + E_;                            // E
    short* Wb    = (short*)(csr_src + E_);                 // bf16 weights

    float* h2out = (float*)d_out;
    float* e2out = h2out + (size_t)N_ * 128;

    prep_weights<<<896, 256, 0, stream>>>(WQ, WK, WV, We, WOh, WOe,
                                          Wh1, Wh2, We1, We2, Wb);
    hipMemsetAsync(cnt, 0, 2 * N_ * sizeof(int), stream);  // cnt + cursor
    hist_kernel<<<E_ / 256, 256, 0, stream>>>(dst, cnt);
    scan_kernel<<<1, 1024, 0, stream>>>(cnt, off);
    scatter_kernel<<<E_ / 256, 256, 0, stream>>>(src, dst, off, cursor,
                                                 slotOf, csr_src);
    qkv_kernel<<<N_ / 64, 256, 0, stream>>>(h, Wb, Qb, Kb, Vb);
    edge_kernel<<<E_ / 64, 256, 0, stream>>>(
        e, src, dst, slotOf, Qb, Kb, sexpS,
        Wb + 3 * 16384, Wb + 5 * 16384,
        Wb + 98304 + 2 * 32768, Wb + 98304 + 3 * 32768,
        bOe, g1e, b1e, be1, be2, g2e, b2e, e2out);
    node_kernel<<<N_ / 64, 256, 0, stream>>>(
        h, Vb, sexpS, off, csr_src,
        Wb + 4 * 16384, Wb + 98304, Wb + 98304 + 32768,
        bOh, g1h, b1h, bh1, bh2, g2h, b2h, h2out);
}

// Round 5
// 767.906 us; speedup vs baseline: 2.2477x; 1.6216x over previous
//
#include <hip/hip_runtime.h>
#include <hip/hip_bf16.h>

// GraphTransformerLayer on MI355X — round 5.
// vs round 4:
//  - Weight B-operands staged per-phase into shared LDS (sW, 34.8KB) once per
//    block instead of every wave re-reading 192KB from L2. XOR chunk swizzle
//    keeps ds_write/ds_read ~conflict-free.
//  - Residuals (e,h) in 32 f32 registers (acc layout) instead of an LDS buffer:
//    LDS/block 52.2KB -> 3 blocks/CU (12 waves/CU vs ~7.4).

constexpr int N_ = 40000;
constexpr int E_ = 640000;

typedef __attribute__((ext_vector_type(8))) short bf16x8;
typedef __attribute__((ext_vector_type(4))) float f32x4;

__device__ inline short f2bf(float f) {
    union { float f; unsigned u; } v; v.f = f;
    unsigned r = v.u + 0x7FFFu + ((v.u >> 16) & 1u);   // RNE
    return (short)(r >> 16);
}
__device__ inline float bf2f(unsigned short u) {
    union { unsigned u; float f; } v; v.u = ((unsigned)u) << 16; return v.f;
}
__device__ inline unsigned packbf2(float a, float b) {
    return (unsigned)(unsigned short)f2bf(a) |
           ((unsigned)(unsigned short)f2bf(b) << 16);
}

__device__ inline f32x4 mfma16(bf16x8 a, bf16x8 b, f32x4 c) {
    return __builtin_amdgcn_mfma_f32_16x16x32_bf16(a, b, c, 0, 0, 0);
}

__device__ inline float red16(float v) {
    v += __shfl_xor(v, 1);
    v += __shfl_xor(v, 2);
    v += __shfl_xor(v, 4);
    v += __shfl_xor(v, 8);
    return v;
}

// sW element offset (shorts) for row `row`, 16B-chunk `chunk` (0..15).
// XOR swizzle on chunk bits with row>>3 so that writes (64 consecutive rows
// per wave) and reads (16 rows at stride 16) are both ~2-way -> free.
__device__ inline int swzW(int row, int chunk) {
    return row * 136 + ((chunk ^ ((row >> 3) & 7)) << 3);
}

template<int KSTEPS, int LDA>
__device__ inline void load_af(const short* sA, int row, int g, bf16x8* af) {
#pragma unroll
    for (int ks = 0; ks < KSTEPS; ++ks)
        af[ks] = *(const bf16x8*)(sA + row * LDA + ks * 32 + g * 8);
}

// One 16-wide N-tile with B from swizzled LDS weight tile.
template<int KSTEPS>
__device__ inline f32x4 gemm_tileL(const bf16x8* af, const short* sW,
                                   int nrow, int g, f32x4 acc) {
#pragma unroll
    for (int ks = 0; ks < KSTEPS; ++ks)
        acc = mfma16(af[ks], *(const bf16x8*)(sW + swzW(nrow, ks * 4 + g)), acc);
    return acc;
}

// Stage a 128x128 bf16 weight tile from global [row][srcK shorts] (+koff)
// into swizzled sW. Fully coalesced 16B loads.
template<int NT>
__device__ inline void stageW(const short* __restrict__ Wsrc, int srcK, int koff,
                              short* sW, int tid) {
    constexpr int TPR = NT / 128;      // threads per row
    constexpr int CH  = 16 / TPR;      // 16B chunks per thread
    int row = tid / TPR;
    int cb = (tid % TPR) * CH;
    const short* sp = Wsrc + row * srcK + koff + cb * 8;
#pragma unroll
    for (int p = 0; p < CH; ++p)
        *(bf16x8*)(sW + swzW(row, cb + p)) = *(const bf16x8*)(sp + p * 8);
}

// Stage this wave's 16 rows of a [*,128] f32 matrix into LDS as bf16.
__device__ inline void stage64(const float* __restrict__ gsrc, short* sA,
                               int lane, int rowB) {
    int rr = rowB + (lane >> 2);
    int c0 = (lane & 3) * 32;
    const float* gp = gsrc + (size_t)rr * 128 + c0;
    short* dp = sA + rr * 136 + c0;
#pragma unroll
    for (int p = 0; p < 4; ++p) {
        float4 x = *(const float4*)(gp + p * 8);
        float4 y = *(const float4*)(gp + p * 8 + 4);
        bf16x8 v;
        v[0] = f2bf(x.x); v[1] = f2bf(x.y); v[2] = f2bf(x.z); v[3] = f2bf(x.w);
        v[4] = f2bf(y.x); v[5] = f2bf(y.y); v[6] = f2bf(y.z); v[7] = f2bf(y.w);
        *(bf16x8*)(dp + p * 8) = v;
    }
}

// x1 = LN(eres + A@W + bias); A bf16 in sA, W staged in sW, eres f32 regs.
__device__ inline void proj_ln(short* sA, const f32x4* eres, const short* sW,
                               const float* __restrict__ bias,
                               const float* __restrict__ gma,
                               const float* __restrict__ beta,
                               int rowB, int c, int g, f32x4* x1v) {
    bf16x8 af[4];
    load_af<4, 136>(sA, rowB + c, g, af);
    float sx[4] = {0, 0, 0, 0}, sxx[4] = {0, 0, 0, 0};
#pragma unroll
    for (int n = 0; n < 8; ++n) {
        f32x4 a = gemm_tileL<4>(af, sW, n * 16 + c, g, f32x4{0.f, 0.f, 0.f, 0.f});
        const int col = n * 16 + c;
        float bo = bias[col];
#pragma unroll
        for (int r = 0; r < 4; ++r) {
            float xv = a[r] + bo + eres[n][r];
            a[r] = xv; sx[r] += xv; sxx[r] += xv * xv;
        }
        x1v[n] = a;
    }
    float mean[4], inv[4];
#pragma unroll
    for (int r = 0; r < 4; ++r) {
        float s = red16(sx[r]), s2 = red16(sxx[r]);
        mean[r] = s * 0.0078125f;
        float var = s2 * 0.0078125f - mean[r] * mean[r];
        inv[r] = rsqrtf(var + 1e-5f);
    }
#pragma unroll
    for (int n = 0; n < 8; ++n) {
        const int col = n * 16 + c;
        float gg = gma[col], bb = beta[col];
#pragma unroll
        for (int r = 0; r < 4; ++r) {
            float v1 = (x1v[n][r] - mean[r]) * inv[r] * gg + bb;
            x1v[n][r] = v1;
            sA[(rowB + g * 4 + r) * 136 + col] = f2bf(v1);
        }
    }
}

// out = LN(x1 + relu(x1@W1 + b1)@W2 + b2); x1 bf16 in sA / f32 in x1v.
// W1 [256][128], W2 [128][256] staged in halves through sW (4 phases).
template<int NT>
__device__ inline void ffn_lnS(short* sA, short* sW,
                               const short* __restrict__ W1t,
                               const float* __restrict__ b1,
                               const short* __restrict__ W2t,
                               const float* __restrict__ b2,
                               const float* __restrict__ gma,
                               const float* __restrict__ beta,
                               int rowB, int c, int g, int tid,
                               f32x4* x1v, float* __restrict__ outp, int tb) {
    bf16x8 af[4];
    load_af<4, 136>(sA, rowB + c, g, af);    // x1 fragments, kept in regs
#pragma unroll
    for (int half = 0; half < 2; ++half) {
        __syncthreads();                     // prior sW consumers done
        stageW<NT>(W1t + half * 128 * 128, 128, 0, sW, tid);
        __syncthreads();
#pragma unroll
        for (int n2 = 0; n2 < 8; ++n2) {
            f32x4 a3 = gemm_tileL<4>(af, sW, n2 * 16 + c, g,
                                     f32x4{0.f, 0.f, 0.f, 0.f});
            const int col2 = half * 128 + n2 * 16 + c;
            float bb = b1[col2];
#pragma unroll
            for (int r = 0; r < 4; ++r)
                sA[(rowB + g * 4 + r) * 136 + n2 * 16 + c] =
                    f2bf(fmaxf(a3[r] + bb, 0.f));
        }
        bf16x8 a4[4];
        load_af<4, 136>(sA, rowB + c, g, a4);   // u half (wave-private rows)
        __syncthreads();
        stageW<NT>(W2t, 256, half * 128, sW, tid);
        __syncthreads();
#pragma unroll
        for (int n = 0; n < 8; ++n)
            x1v[n] = gemm_tileL<4>(a4, sW, n * 16 + c, g, x1v[n]);
    }
    float ty[4] = {0, 0, 0, 0}, tyy[4] = {0, 0, 0, 0};
#pragma unroll
    for (int n = 0; n < 8; ++n) {
        const int col = n * 16 + c;
        float bb = b2[col];
#pragma unroll
        for (int r = 0; r < 4; ++r) {
            float xv = x1v[n][r] + bb;
            x1v[n][r] = xv; ty[r] += xv; tyy[r] += xv * xv;
        }
    }
    float mean[4], inv[4];
#pragma unroll
    for (int r = 0; r < 4; ++r) {
        float s = red16(ty[r]), s2 = red16(tyy[r]);
        mean[r] = s * 0.0078125f;
        float var = s2 * 0.0078125f - mean[r] * mean[r];
        inv[r] = rsqrtf(var + 1e-5f);
    }
#pragma unroll
    for (int n = 0; n < 8; ++n) {
        const int col = n * 16 + c;
        float gg = gma[col], bb = beta[col];
#pragma unroll
        for (int r = 0; r < 4; ++r)
            outp[(size_t)(tb + rowB + g * 4 + r) * 128 + col] =
                (x1v[n][r] - mean[r]) * inv[r] * gg + bb;
    }
}

// ---------------------------------------------------------------- prep
__global__ void prep_weights(
    const float* __restrict__ WQ, const float* __restrict__ WK,
    const float* __restrict__ WV, const float* __restrict__ We,
    const float* __restrict__ WOh, const float* __restrict__ WOe,
    const float* __restrict__ Wh1, const float* __restrict__ Wh2,
    const float* __restrict__ We1, const float* __restrict__ We2,
    short* __restrict__ out) {
    int i = blockIdx.x * 256 + threadIdx.x;
    if (i < 98304) {
        int m = i >> 14, j = i & 16383;
        int n = j >> 7, k = j & 127;
        const float* W = m == 0 ? WQ : m == 1 ? WK : m == 2 ? WV
                        : m == 3 ? We : m == 4 ? WOh : WOe;
        out[i] = f2bf(W[k * 128 + n]);
    } else if (i < 229376) {
        int j = i - 98304;
        int m = j >> 15; j &= 32767;
        const float* W = m == 0 ? Wh1 : m == 1 ? Wh2 : m == 2 ? We1 : We2;
        int ks = (m == 0 || m == 2) ? 7 : 8;       // Kin = 128 or 256
        int n = j >> ks, k = j & ((1 << ks) - 1);
        int Nout = 32768 >> ks;
        out[i] = f2bf(W[k * Nout + n]);
    }
}

// ---------------------------------------------------------------- CSR build
__global__ void hist_kernel(const int* __restrict__ dst, int* __restrict__ cnt) {
    int i = blockIdx.x * 256 + threadIdx.x;
    if (i < E_) atomicAdd(&cnt[dst[i]], 1);
}

__global__ void __launch_bounds__(1024) scan_kernel(const int* __restrict__ cnt,
                                                    int* __restrict__ off) {
    __shared__ int part[1024];
    int t = threadIdx.x;
    int base = t * 40;
    int s = 0;
    if (base < N_) {
        int end = min(base + 40, N_);
        for (int i = base; i < end; ++i) s += cnt[i];
    }
    part[t] = s;
    __syncthreads();
    for (int d = 1; d < 1024; d <<= 1) {
        int v = (t >= d) ? part[t - d] : 0;
        __syncthreads();
        part[t] += v;
        __syncthreads();
    }
    int prefix = (t == 0) ? 0 : part[t - 1];
    if (base < N_) {
        int end = min(base + 40, N_);
        int run = prefix;
        for (int i = base; i < end; ++i) { off[i] = run; run += cnt[i]; }
    }
    if (t == 1023) off[N_] = part[1023];
}

__global__ void scatter_kernel(const int* __restrict__ src,
                               const int* __restrict__ dst,
                               const int* __restrict__ off,
                               int* __restrict__ cursor,
                               int* __restrict__ slotOf,
                               int* __restrict__ csr_src) {
    int i = blockIdx.x * 256 + threadIdx.x;
    if (i < E_) {
        int d = dst[i];
        int s = off[d] + atomicAdd(&cursor[d], 1);
        slotOf[i] = s;
        csr_src[s] = src[i];
    }
}

// ---------------------------------------------------------------- QKV (bf16 out)
__global__ void __launch_bounds__(256) qkv_kernel(
    const float* __restrict__ hsrc, const short* __restrict__ Wt3,
    unsigned short* __restrict__ Qo, unsigned short* __restrict__ Ko,
    unsigned short* __restrict__ Vo) {
    __shared__ __align__(16) short sA[64 * 136];
    __shared__ __align__(16) short sW[128 * 136];
    const int tid = threadIdx.x;
    const int tb = blockIdx.x * 64;
    const int lane = tid & 63, wave = tid >> 6;
    const int c = lane & 15, g = lane >> 4;
    const int rowB = wave * 16;

    stage64(hsrc + (size_t)tb * 128, sA, lane, rowB);
    bf16x8 af[4];
    load_af<4, 136>(sA, rowB + c, g, af);

    unsigned short* outs[3] = {Qo, Ko, Vo};
#pragma unroll
    for (int w = 0; w < 3; ++w) {
        __syncthreads();
        stageW<256>(Wt3 + w * 16384, 128, 0, sW, tid);
        __syncthreads();
        unsigned short* op = outs[w];
#pragma unroll
        for (int n = 0; n < 8; ++n) {
            f32x4 a = gemm_tileL<4>(af, sW, n * 16 + c, g,
                                    f32x4{0.f, 0.f, 0.f, 0.f});
            const int col = n * 16 + c;
#pragma unroll
            for (int r = 0; r < 4; ++r)
                op[(size_t)(tb + rowB + g * 4 + r) * 128 + col] =
                    (unsigned short)f2bf(a[r]);
        }
    }
}

// ---------------------------------------------------------------- edges
__global__ void __launch_bounds__(256) edge_kernel(
    const float* __restrict__ e, const int* __restrict__ src,
    const int* __restrict__ dst, const int* __restrict__ slotOf,
    const unsigned short* __restrict__ Qb, const unsigned short* __restrict__ Kb,
    float* __restrict__ sexpS,
    const short* __restrict__ Wet, const short* __restrict__ WOet,
    const short* __restrict__ We1t, const short* __restrict__ We2t,
    const float* __restrict__ bOe,
    const float* __restrict__ g1e, const float* __restrict__ b1e,
    const float* __restrict__ be1, const float* __restrict__ be2,
    const float* __restrict__ g2e, const float* __restrict__ b2e,
    float* __restrict__ e2out) {
    __shared__ __align__(16) short sA[64 * 136];   // e -> pe -> score -> x1 -> u
    __shared__ __align__(16) short sW[128 * 136];  // per-phase weight tile
    const int tid = threadIdx.x;
    const int tb = blockIdx.x * 64;
    const int lane = tid & 63, wave = tid >> 6;
    const int c = lane & 15, g = lane >> 4;
    const int rowB = wave * 16;

    stage64(e + (size_t)tb * 128, sA, lane, rowB);
    stageW<256>(Wet, 128, 0, sW, tid);

    // preload this wave's 16 src / 16 dst / 16 slot indices (lane-partitioned)
    int pre = 0;
    {
        int li = lane & 15;
        if (lane < 16)       pre = src[tb + rowB + li];
        else if (lane < 32)  pre = dst[tb + rowB + li];
        else if (lane < 48)  pre = slotOf[tb + rowB + li];
    }

    // residual e in registers (acc layout), issued early
    f32x4 eres[8];
#pragma unroll
    for (int n = 0; n < 8; ++n)
#pragma unroll
        for (int r = 0; r < 4; ++r)
            eres[n][r] = e[(size_t)(tb + rowB + g * 4 + r) * 128 + n * 16 + c];

    __syncthreads();     // sW(We) staged

    // GEMM1: pe = e @ We -> stash bf16 into sA (wave-private rows)
    bf16x8 af[4];
    load_af<4, 136>(sA, rowB + c, g, af);
#pragma unroll
    for (int n = 0; n < 8; ++n) {
        f32x4 p = gemm_tileL<4>(af, sW, n * 16 + c, g, f32x4{0.f, 0.f, 0.f, 0.f});
#pragma unroll
        for (int r = 0; r < 4; ++r)
            sA[(rowB + g * 4 + r) * 136 + n * 16 + c] = f2bf(p[r]);
    }

    // ---- score phase: 2 batches of 8 edges; gathers issued 16-deep
    const int head = lane >> 3;
#pragma unroll
    for (int b = 0; b < 2; ++b) {
        unsigned kreg[8], qreg[8];
#pragma unroll
        for (int k = 0; k < 8; ++k) {
            int sI = __shfl(pre, b * 8 + k);
            kreg[k] = *(const unsigned*)(Kb + (size_t)sI * 128 + 2 * lane);
        }
#pragma unroll
        for (int k = 0; k < 8; ++k) {
            int dI = __shfl(pre, 16 + b * 8 + k);
            qreg[k] = *(const unsigned*)(Qb + (size_t)dI * 128 + 2 * lane);
        }
#pragma unroll
        for (int k = 0; k < 8; ++k) {
            const int i = b * 8 + k;
            const int row = rowB + i;
            const int slot = __shfl(pre, 32 + i);   // full-exec shfl
            unsigned pp = *(const unsigned*)(sA + row * 136 + 2 * lane);
            float sc0 = bf2f((unsigned short)kreg[k]) *
                        bf2f((unsigned short)qreg[k]) * 0.25f *
                        bf2f((unsigned short)pp);
            float sc1 = bf2f((unsigned short)(kreg[k] >> 16)) *
                        bf2f((unsigned short)(qreg[k] >> 16)) * 0.25f *
                        bf2f((unsigned short)(pp >> 16));
            *(unsigned*)(sA + row * 136 + 2 * lane) = packbf2(sc0, sc1);
            float s = sc0 + sc1;
            s += __shfl_xor(s, 1);
            s += __shfl_xor(s, 2);
            s += __shfl_xor(s, 4);
            s = fminf(5.f, fmaxf(-5.f, s));
            if ((lane & 7) == 0)
                sexpS[(size_t)slot * 8 + head] = __expf(s);
        }
    }

    __syncthreads();     // all waves done with sW(We)
    stageW<256>(WOet, 128, 0, sW, tid);
    __syncthreads();

    f32x4 x1v[8];
    proj_ln(sA, eres, sW, bOe, g1e, b1e, rowB, c, g, x1v);
    ffn_lnS<256>(sA, sW, We1t, be1, We2t, be2, g2e, b2e,
                 rowB, c, g, tid, x1v, e2out, tb);
}

// ---------------------------------------------------------------- nodes
__global__ void __launch_bounds__(256) node_kernel(
    const float* __restrict__ h, const unsigned short* __restrict__ Vb,
    const float* __restrict__ sexpS,
    const int* __restrict__ off, const int* __restrict__ csr_src,
    const short* __restrict__ WOht, const short* __restrict__ Wh1t,
    const short* __restrict__ Wh2t,
    const float* __restrict__ bOh,
    const float* __restrict__ g1h, const float* __restrict__ b1h,
    const float* __restrict__ bh1, const float* __restrict__ bh2,
    const float* __restrict__ g2h, const float* __restrict__ b2h,
    float* __restrict__ h2out) {
    __shared__ __align__(16) short sA[64 * 136];
    __shared__ __align__(16) short sW[128 * 136];
    const int tid = threadIdx.x;
    const int tb = blockIdx.x * 64;
    const int lane = tid & 63, wave = tid >> 6;
    const int c = lane & 15, g = lane >> 4;
    const int rowB = wave * 16;
    const int head = lane >> 3;

    stageW<256>(WOht, 128, 0, sW, tid);     // overlaps the pull phase

    // residual h in registers (acc layout)
    f32x4 hres[8];
#pragma unroll
    for (int n = 0; n < 8; ++n)
#pragma unroll
        for (int r = 0; r < 4; ++r)
            hres[n][r] = h[(size_t)(tb + rowB + g * 4 + r) * 128 + n * 16 + c];

    // preload CSR offsets for this wave's 16 nodes (+1)
    int offv = (lane < 17) ? off[tb + rowB + lane] : 0;

    // phase A: pull-reduce h_attn, batched 8-wide
    for (int i = 0; i < 16; ++i) {
        const int b0 = __shfl(offv, i), b1 = __shfl(offv, i + 1);
        float a0 = 0.f, a1 = 0.f, zz = 0.f;
        for (int j0 = b0; j0 < b1; j0 += 8) {
            int jj = j0 + (lane & 7);
            int ci = (jj < b1) ? csr_src[jj] : 0;
            unsigned vv[8]; float sv[8];
#pragma unroll
            for (int k = 0; k < 8; ++k) {
                bool ok = (j0 + k) < b1;
                int cs = __shfl(ci, k);
                vv[k] = ok ? *(const unsigned*)(Vb + (size_t)cs * 128 + 2 * lane)
                           : 0u;
                sv[k] = ok ? sexpS[(size_t)(j0 + k) * 8 + head] : 0.f;
            }
#pragma unroll
            for (int k = 0; k < 8; ++k) {
                a0 += bf2f((unsigned short)vv[k]) * sv[k];
                a1 += bf2f((unsigned short)(vv[k] >> 16)) * sv[k];
                zz += sv[k];
            }
        }
        float iz = 1.f / (zz + 1e-6f);
        *(unsigned*)(sA + (rowB + i) * 136 + 2 * lane) = packbf2(a0 * iz, a1 * iz);
    }

    __syncthreads();     // sW(WOh) staged (pull phase covered the latency)

    f32x4 x1v[8];
    proj_ln(sA, hres, sW, bOh, g1h, b1h, rowB, c, g, x1v);
    ffn_lnS<256>(sA, sW, Wh1t, bh1, Wh2t, bh2, g2h, b2h,
                 rowB, c, g, tid, x1v, h2out, tb);
}

// ---------------------------------------------------------------- launch
extern "C" void kernel_launch(void* const* d_in, const int* in_sizes, int n_in,
                              void* d_out, int out_size, void* d_ws,
                              size_t ws_size, hipStream_t stream) {
    const float* h   = (const float*)d_in[0];
    const float* e   = (const float*)d_in[1];
    const int*   src = (const int*)d_in[2];
    const int*   dst = (const int*)d_in[3];
    const float* WQ  = (const float*)d_in[4];
    const float* WK  = (const float*)d_in[5];
    const float* WV  = (const float*)d_in[6];
    const float* We  = (const float*)d_in[7];
    const float* WOh = (const float*)d_in[8];
    const float* bOh = (const float*)d_in[9];
    const float* WOe = (const float*)d_in[10];
    const float* bOe = (const float*)d_in[11];
    const float* g1h = (const float*)d_in[12];
    const float* b1h = (const float*)d_in[13];
    const float* g1e = (const float*)d_in[14];
    const float* b1e = (const float*)d_in[15];
    const float* Wh1 = (const float*)d_in[16];
    const float* bh1 = (const float*)d_in[17];
    const float* Wh2 = (const float*)d_in[18];
    const float* bh2 = (const float*)d_in[19];
    const float* We1 = (const float*)d_in[20];
    const float* be1 = (const float*)d_in[21];
    const float* We2 = (const float*)d_in[22];
    const float* be2 = (const float*)d_in[23];
    const float* g2h = (const float*)d_in[24];
    const float* b2h = (const float*)d_in[25];
    const float* g2e = (const float*)d_in[26];
    const float* b2e = (const float*)d_in[27];

    unsigned short* Qb = (unsigned short*)d_ws;            // N*128 bf16
    unsigned short* Kb = Qb + (size_t)N_ * 128;
    unsigned short* Vb = Kb + (size_t)N_ * 128;
    float* sexpS = (float*)(Vb + (size_t)N_ * 128);        // E*8 (CSR slot order)
    int* cnt     = (int*)(sexpS + (size_t)E_ * 8);         // N
    int* cursor  = cnt + N_;                               // N
    int* off     = cursor + N_;                            // N+1
    int* slotOf  = off + N_ + 1;                           // E
    int* csr_src = slotOf + E_;                            // E
    short* Wb    = (short*)(csr_src + E_);                 // bf16 weights

    float* h2out = (float*)d_out;
    float* e2out = h2out + (size_t)N_ * 128;

    prep_weights<<<896, 256, 0, stream>>>(WQ, WK, WV, We, WOh, WOe,
                                          Wh1, Wh2, We1, We2, Wb);
    hipMemsetAsync(cnt, 0, 2 * N_ * sizeof(int), stream);  // cnt + cursor
    hist_kernel<<<E_ / 256, 256, 0, stream>>>(dst, cnt);
    scan_kernel<<<1, 1024, 0, stream>>>(cnt, off);
    scatter_kernel<<<E_ / 256, 256, 0, stream>>>(src, dst, off, cursor,
                                                 slotOf, csr_src);
    qkv_kernel<<<N_ / 64, 256, 0, stream>>>(h, Wb, Qb, Kb, Vb);
    edge_kernel<<<E_ / 64, 256, 0, stream>>>(
        e, src, dst, slotOf, Qb, Kb, sexpS,
        Wb + 3 * 16384, Wb + 5 * 16384,
        Wb + 98304 + 2 * 32768, Wb + 98304 + 3 * 32768,
        bOe, g1e, b1e, be1, be2, g2e, b2e, e2out);
    node_kernel<<<N_ / 64, 256, 0, stream>>>(
        h, Vb, sexpS, off, csr_src,
        Wb + 4 * 16384, Wb + 98304, Wb + 98304 + 32768,
        bOh, g1h, b1h, bh1, bh2, g2h, b2h, h2out);
}

// Round 7
// 530.282 us; speedup vs baseline: 3.2549x; 1.4481x over previous
//
#include <hip/hip_runtime.h>
#include <hip/hip_bf16.h>

// GraphTransformerLayer on MI355X — round 7.
// = round 6 (fragment-ordered weights, conflict-free LDS) but staging via
// explicit b128 loads + linear ds_writes instead of global_load_lds (r6's
// 8-distinct-LDS-base unrolled builtin usage produced stale sW blocks).

constexpr int N_ = 40000;
constexpr int E_ = 640000;

typedef __attribute__((ext_vector_type(8))) short bf16x8;
typedef __attribute__((ext_vector_type(4))) float f32x4;

__device__ inline short f2bf(float f) {
    union { float f; unsigned u; } v; v.f = f;
    unsigned r = v.u + 0x7FFFu + ((v.u >> 16) & 1u);   // RNE
    return (short)(r >> 16);
}
__device__ inline float bf2f(unsigned short u) {
    union { unsigned u; float f; } v; v.u = ((unsigned)u) << 16; return v.f;
}
__device__ inline unsigned packbf2(float a, float b) {
    return (unsigned)(unsigned short)f2bf(a) |
           ((unsigned)(unsigned short)f2bf(b) << 16);
}

__device__ inline f32x4 mfma16(bf16x8 a, bf16x8 b, f32x4 c) {
    return __builtin_amdgcn_mfma_f32_16x16x32_bf16(a, b, c, 0, 0, 0);
}

__device__ inline float red16(float v) {
    v += __shfl_xor(v, 1);
    v += __shfl_xor(v, 2);
    v += __shfl_xor(v, 4);
    v += __shfl_xor(v, 8);
    return v;
}

template<int KSTEPS, int LDA>
__device__ inline void load_af(const short* sA, int row, int g, bf16x8* af) {
#pragma unroll
    for (int ks = 0; ks < KSTEPS; ++ks)
        af[ks] = *(const bf16x8*)(sA + row * LDA + ks * 32 + g * 8);
}

// B-fragments from fragment-ordered LDS tile: block (n*4+ks) is 1024B,
// lane reads its own contiguous 16B slot. Conflict-free.
template<int KSTEPS>
__device__ inline f32x4 gemm_tileF(const bf16x8* af, const short* sW,
                                   int n, int lane, f32x4 acc) {
#pragma unroll
    for (int ks = 0; ks < KSTEPS; ++ks)
        acc = mfma16(af[ks],
                     *(const bf16x8*)(sW + ((n * 4 + ks) * 64 + lane) * 8), acc);
    return acc;
}

// Linear 32KB copy global(fragment-ordered) -> LDS, explicit reg staging.
// Thread t copies 16B chunks t, t+256, ..., t+1792: coalesced global b128
// loads, lane-contiguous ds_write_b128 (conflict-free).
__device__ inline void stageWX(const short* __restrict__ Wsrc, short* sW,
                               int tid) {
    bf16x8 tmp[8];
#pragma unroll
    for (int p = 0; p < 8; ++p)
        tmp[p] = *(const bf16x8*)(Wsrc + (tid + p * 256) * 8);
#pragma unroll
    for (int p = 0; p < 8; ++p)
        *(bf16x8*)(sW + (tid + p * 256) * 8) = tmp[p];
}

// Stage this wave's 16 rows of a [*,128] f32 matrix into LDS as bf16.
__device__ inline void stage64(const float* __restrict__ gsrc, short* sA,
                               int lane, int rowB) {
    int rr = rowB + (lane >> 2);
    int c0 = (lane & 3) * 32;
    const float* gp = gsrc + (size_t)rr * 128 + c0;
    short* dp = sA + rr * 136 + c0;
#pragma unroll
    for (int p = 0; p < 4; ++p) {
        float4 x = *(const float4*)(gp + p * 8);
        float4 y = *(const float4*)(gp + p * 8 + 4);
        bf16x8 v;
        v[0] = f2bf(x.x); v[1] = f2bf(x.y); v[2] = f2bf(x.z); v[3] = f2bf(x.w);
        v[4] = f2bf(y.x); v[5] = f2bf(y.y); v[6] = f2bf(y.z); v[7] = f2bf(y.w);
        *(bf16x8*)(dp + p * 8) = v;
    }
}

// x1 = LN(eres + A@W + bias); A bf16 in sA, W fragment-ordered in sW.
__device__ inline void proj_ln(short* sA, const f32x4* eres, const short* sW,
                               const float* __restrict__ bias,
                               const float* __restrict__ gma,
                               const float* __restrict__ beta,
                               int rowB, int c, int g, int lane, f32x4* x1v) {
    bf16x8 af[4];
    load_af<4, 136>(sA, rowB + c, g, af);
    float sx[4] = {0, 0, 0, 0}, sxx[4] = {0, 0, 0, 0};
#pragma unroll
    for (int n = 0; n < 8; ++n) {
        f32x4 a = gemm_tileF<4>(af, sW, n, lane, f32x4{0.f, 0.f, 0.f, 0.f});
        const int col = n * 16 + c;
        float bo = bias[col];
#pragma unroll
        for (int r = 0; r < 4; ++r) {
            float xv = a[r] + bo + eres[n][r];
            a[r] = xv; sx[r] += xv; sxx[r] += xv * xv;
        }
        x1v[n] = a;
    }
    float mean[4], inv[4];
#pragma unroll
    for (int r = 0; r < 4; ++r) {
        float s = red16(sx[r]), s2 = red16(sxx[r]);
        mean[r] = s * 0.0078125f;
        float var = s2 * 0.0078125f - mean[r] * mean[r];
        inv[r] = rsqrtf(var + 1e-5f);
    }
#pragma unroll
    for (int n = 0; n < 8; ++n) {
        const int col = n * 16 + c;
        float gg = gma[col], bb = beta[col];
#pragma unroll
        for (int r = 0; r < 4; ++r) {
            float v1 = (x1v[n][r] - mean[r]) * inv[r] * gg + bb;
            x1v[n][r] = v1;
            sA[(rowB + g * 4 + r) * 136 + col] = f2bf(v1);
        }
    }
}

// out = LN(x1 + relu(x1@W1 + b1)@W2 + b2); W1/W2 staged in 32KB halves.
__device__ inline void ffn_lnS(short* sA, short* sW,
                               const short* __restrict__ W1t,
                               const float* __restrict__ b1,
                               const short* __restrict__ W2t,
                               const float* __restrict__ b2,
                               const float* __restrict__ gma,
                               const float* __restrict__ beta,
                               int rowB, int c, int g, int lane, int tid,
                               f32x4* x1v, float* __restrict__ outp, int tb) {
    bf16x8 af[4];
    load_af<4, 136>(sA, rowB + c, g, af);    // x1 fragments, kept in regs
#pragma unroll
    for (int half = 0; half < 2; ++half) {
        __syncthreads();                     // prior sW consumers done
        stageWX(W1t + half * 16384, sW, tid);
        __syncthreads();
#pragma unroll
        for (int n2 = 0; n2 < 8; ++n2) {
            f32x4 a3 = gemm_tileF<4>(af, sW, n2, lane,
                                     f32x4{0.f, 0.f, 0.f, 0.f});
            const int col2 = half * 128 + n2 * 16 + c;
            float bb = b1[col2];
#pragma unroll
            for (int r = 0; r < 4; ++r)
                sA[(rowB + g * 4 + r) * 136 + n2 * 16 + c] =
                    f2bf(fmaxf(a3[r] + bb, 0.f));
        }
        bf16x8 a4[4];
        load_af<4, 136>(sA, rowB + c, g, a4);   // u half (wave-private rows)
        __syncthreads();
        stageWX(W2t + half * 16384, sW, tid);
        __syncthreads();
#pragma unroll
        for (int n = 0; n < 8; ++n)
            x1v[n] = gemm_tileF<4>(a4, sW, n, lane, x1v[n]);
    }
    float ty[4] = {0, 0, 0, 0}, tyy[4] = {0, 0, 0, 0};
#pragma unroll
    for (int n = 0; n < 8; ++n) {
        const int col = n * 16 + c;
        float bb = b2[col];
#pragma unroll
        for (int r = 0; r < 4; ++r) {
            float xv = x1v[n][r] + bb;
            x1v[n][r] = xv; ty[r] += xv; tyy[r] += xv * xv;
        }
    }
    float mean[4], inv[4];
#pragma unroll
    for (int r = 0; r < 4; ++r) {
        float s = red16(ty[r]), s2 = red16(tyy[r]);
        mean[r] = s * 0.0078125f;
        float var = s2 * 0.0078125f - mean[r] * mean[r];
        inv[r] = rsqrtf(var + 1e-5f);
    }
#pragma unroll
    for (int n = 0; n < 8; ++n) {
        const int col = n * 16 + c;
        float gg = gma[col], bb = beta[col];
#pragma unroll
        for (int r = 0; r < 4; ++r)
            outp[(size_t)(tb + rowB + g * 4 + r) * 128 + col] =
                (x1v[n][r] - mean[r]) * inv[r] * gg + bb;
    }
}

// ---------------------------------------------------------------- prep
// Emit weights in MFMA fragment order (see gemm_tileF).
// Layout: 6x 16384 (WQ,WK,WV,We,WOh,WOe), then Wh1,Wh2,We1,We2 (32768 each;
// W1 mats as two col-halves, W2 mats as two k-halves, each half 16384).
__global__ void prep_weights(
    const float* __restrict__ WQ, const float* __restrict__ WK,
    const float* __restrict__ WV, const float* __restrict__ We,
    const float* __restrict__ WOh, const float* __restrict__ WOe,
    const float* __restrict__ Wh1, const float* __restrict__ Wh2,
    const float* __restrict__ We1, const float* __restrict__ We2,
    short* __restrict__ out) {
    int i = blockIdx.x * 256 + threadIdx.x;
    if (i < 98304) {
        int m = i >> 14, r = i & 16383;
        const float* W = m == 0 ? WQ : m == 1 ? WK : m == 2 ? WV
                        : m == 3 ? We : m == 4 ? WOh : WOe;
        int blk = r >> 9, l = (r >> 3) & 63, j = r & 7;
        int n = blk >> 2, ks = blk & 3;
        int col = n * 16 + (l & 15);
        int k = ks * 32 + (l >> 4) * 8 + j;
        out[i] = f2bf(W[k * 128 + col]);
    } else if (i < 229376) {
        int j2 = i - 98304;
        int m = j2 >> 15, r = j2 & 32767;
        int half = r >> 14, q = r & 16383;
        int blk = q >> 9, l = (q >> 3) & 63, j = q & 7;
        int n = blk >> 2, ks = blk & 3;
        if (m == 0 || m == 2) {                    // W1-type [128][256]
            const float* W = (m == 0) ? Wh1 : We1;
            int col2 = half * 128 + n * 16 + (l & 15);
            int k = ks * 32 + (l >> 4) * 8 + j;
            out[i] = f2bf(W[k * 256 + col2]);
        } else {                                   // W2-type [256][128]
            const float* W = (m == 1) ? Wh2 : We2;
            int col = n * 16 + (l & 15);
            int k = half * 128 + ks * 32 + (l >> 4) * 8 + j;
            out[i] = f2bf(W[k * 128 + col]);
        }
    }
}

// ---------------------------------------------------------------- CSR build
__global__ void hist_kernel(const int* __restrict__ dst, int* __restrict__ cnt) {
    int i = blockIdx.x * 256 + threadIdx.x;
    if (i < E_) atomicAdd(&cnt[dst[i]], 1);
}

__global__ void __launch_bounds__(1024) scan_kernel(const int* __restrict__ cnt,
                                                    int* __restrict__ off) {
    __shared__ int part[1024];
    int t = threadIdx.x;
    int base = t * 40;
    int s = 0;
    if (base < N_) {
        int end = min(base + 40, N_);
        for (int i = base; i < end; ++i) s += cnt[i];
    }
    part[t] = s;
    __syncthreads();
    for (int d = 1; d < 1024; d <<= 1) {
        int v = (t >= d) ? part[t - d] : 0;
        __syncthreads();
        part[t] += v;
        __syncthreads();
    }
    int prefix = (t == 0) ? 0 : part[t - 1];
    if (base < N_) {
        int end = min(base + 40, N_);
        int run = prefix;
        for (int i = base; i < end; ++i) { off[i] = run; run += cnt[i]; }
    }
    if (t == 1023) off[N_] = part[1023];
}

__global__ void scatter_kernel(const int* __restrict__ src,
                               const int* __restrict__ dst,
                               const int* __restrict__ off,
                               int* __restrict__ cursor,
                               int* __restrict__ slotOf,
                               int* __restrict__ csr_src) {
    int i = blockIdx.x * 256 + threadIdx.x;
    if (i < E_) {
        int d = dst[i];
        int s = off[d] + atomicAdd(&cursor[d], 1);
        slotOf[i] = s;
        csr_src[s] = src[i];
    }
}

// ---------------------------------------------------------------- QKV (bf16 out)
__global__ void __launch_bounds__(256) qkv_kernel(
    const float* __restrict__ hsrc, const short* __restrict__ Wt3,
    unsigned short* __restrict__ Qo, unsigned short* __restrict__ Ko,
    unsigned short* __restrict__ Vo) {
    __shared__ __align__(16) short sA[64 * 136];
    __shared__ __align__(16) short sW[128 * 128];
    const int tid = threadIdx.x;
    const int tb = blockIdx.x * 64;
    const int lane = tid & 63, wave = tid >> 6;
    const int c = lane & 15, g = lane >> 4;
    const int rowB = wave * 16;

    stage64(hsrc + (size_t)tb * 128, sA, lane, rowB);
    bf16x8 af[4];
    load_af<4, 136>(sA, rowB + c, g, af);

    unsigned short* outs[3] = {Qo, Ko, Vo};
#pragma unroll
    for (int w = 0; w < 3; ++w) {
        __syncthreads();
        stageWX(Wt3 + w * 16384, sW, tid);
        __syncthreads();
        unsigned short* op = outs[w];
#pragma unroll
        for (int n = 0; n < 8; ++n) {
            f32x4 a = gemm_tileF<4>(af, sW, n, lane, f32x4{0.f, 0.f, 0.f, 0.f});
            const int col = n * 16 + c;
#pragma unroll
            for (int r = 0; r < 4; ++r)
                op[(size_t)(tb + rowB + g * 4 + r) * 128 + col] =
                    (unsigned short)f2bf(a[r]);
        }
    }
}

// ---------------------------------------------------------------- edges
__global__ void __launch_bounds__(256) edge_kernel(
    const float* __restrict__ e, const int* __restrict__ src,
    const int* __restrict__ dst, const int* __restrict__ slotOf,
    const unsigned short* __restrict__ Qb, const unsigned short* __restrict__ Kb,
    float* __restrict__ sexpS,
    const short* __restrict__ Wet, const short* __restrict__ WOet,
    const short* __restrict__ We1t, const short* __restrict__ We2t,
    const float* __restrict__ bOe,
    const float* __restrict__ g1e, const float* __restrict__ b1e,
    const float* __restrict__ be1, const float* __restrict__ be2,
    const float* __restrict__ g2e, const float* __restrict__ b2e,
    float* __restrict__ e2out) {
    __shared__ __align__(16) short sA[64 * 136];   // e -> pe -> score -> x1 -> u
    __shared__ __align__(16) short sW[128 * 128];  // per-phase weight tile
    const int tid = threadIdx.x;
    const int tb = blockIdx.x * 64;
    const int lane = tid & 63, wave = tid >> 6;
    const int c = lane & 15, g = lane >> 4;
    const int rowB = wave * 16;

    stageWX(Wet, sW, tid);
    stage64(e + (size_t)tb * 128, sA, lane, rowB);

    // preload this wave's 16 src / 16 dst / 16 slot indices (lane-partitioned)
    int pre = 0;
    {
        int li = lane & 15;
        if (lane < 16)       pre = src[tb + rowB + li];
        else if (lane < 32)  pre = dst[tb + rowB + li];
        else if (lane < 48)  pre = slotOf[tb + rowB + li];
    }

    // residual e in registers (acc layout), issued early
    f32x4 eres[8];
#pragma unroll
    for (int n = 0; n < 8; ++n)
#pragma unroll
        for (int r = 0; r < 4; ++r)
            eres[n][r] = e[(size_t)(tb + rowB + g * 4 + r) * 128 + n * 16 + c];

    __syncthreads();     // sW(We) staged

    // GEMM1: pe = e @ We -> stash bf16 into sA (wave-private rows)
    bf16x8 af[4];
    load_af<4, 136>(sA, rowB + c, g, af);
#pragma unroll
    for (int n = 0; n < 8; ++n) {
        f32x4 p = gemm_tileF<4>(af, sW, n, lane, f32x4{0.f, 0.f, 0.f, 0.f});
#pragma unroll
        for (int r = 0; r < 4; ++r)
            sA[(rowB + g * 4 + r) * 136 + n * 16 + c] = f2bf(p[r]);
    }

    // ---- score phase: 2 batches of 8 edges; gathers issued 16-deep
    const int head = lane >> 3;
#pragma unroll
    for (int b = 0; b < 2; ++b) {
        unsigned kreg[8], qreg[8];
#pragma unroll
        for (int k = 0; k < 8; ++k) {
            int sI = __shfl(pre, b * 8 + k);
            kreg[k] = *(const unsigned*)(Kb + (size_t)sI * 128 + 2 * lane);
        }
#pragma unroll
        for (int k = 0; k < 8; ++k) {
            int dI = __shfl(pre, 16 + b * 8 + k);
            qreg[k] = *(const unsigned*)(Qb + (size_t)dI * 128 + 2 * lane);
        }
#pragma unroll
        for (int k = 0; k < 8; ++k) {
            const int i = b * 8 + k;
            const int row = rowB + i;
            const int slot = __shfl(pre, 32 + i);   // full-exec shfl
            unsigned pp = *(const unsigned*)(sA + row * 136 + 2 * lane);
            float sc0 = bf2f((unsigned short)kreg[k]) *
                        bf2f((unsigned short)qreg[k]) * 0.25f *
                        bf2f((unsigned short)pp);
            float sc1 = bf2f((unsigned short)(kreg[k] >> 16)) *
                        bf2f((unsigned short)(qreg[k] >> 16)) * 0.25f *
                        bf2f((unsigned short)(pp >> 16));
            *(unsigned*)(sA + row * 136 + 2 * lane) = packbf2(sc0, sc1);
            float s = sc0 + sc1;
            s += __shfl_xor(s, 1);
            s += __shfl_xor(s, 2);
            s += __shfl_xor(s, 4);
            s = fminf(5.f, fmaxf(-5.f, s));
            if ((lane & 7) == 0)
                sexpS[(size_t)slot * 8 + head] = __expf(s);
        }
    }

    __syncthreads();     // all waves done with sW(We)
    stageWX(WOet, sW, tid);
    __syncthreads();

    f32x4 x1v[8];
    proj_ln(sA, eres, sW, bOe, g1e, b1e, rowB, c, g, lane, x1v);
    ffn_lnS(sA, sW, We1t, be1, We2t, be2, g2e, b2e,
            rowB, c, g, lane, tid, x1v, e2out, tb);
}

// ---------------------------------------------------------------- nodes
__global__ void __launch_bounds__(256) node_kernel(
    const float* __restrict__ h, const unsigned short* __restrict__ Vb,
    const float* __restrict__ sexpS,
    const int* __restrict__ off, const int* __restrict__ csr_src,
    const short* __restrict__ WOht, const short* __restrict__ Wh1t,
    const short* __restrict__ Wh2t,
    const float* __restrict__ bOh,
    const float* __restrict__ g1h, const float* __restrict__ b1h,
    const float* __restrict__ bh1, const float* __restrict__ bh2,
    const float* __restrict__ g2h, const float* __restrict__ b2h,
    float* __restrict__ h2out) {
    __shared__ __align__(16) short sA[64 * 136];
    __shared__ __align__(16) short sW[128 * 128];
    const int tid = threadIdx.x;
    const int tb = blockIdx.x * 64;
    const int lane = tid & 63, wave = tid >> 6;
    const int c = lane & 15, g = lane >> 4;
    const int rowB = wave * 16;
    const int head = lane >> 3;

    stageWX(WOht, sW, tid);     // overlapped with the pull phase

    // residual h in registers (acc layout)
    f32x4 hres[8];
#pragma unroll
    for (int n = 0; n < 8; ++n)
#pragma unroll
        for (int r = 0; r < 4; ++r)
            hres[n][r] = h[(size_t)(tb + rowB + g * 4 + r) * 128 + n * 16 + c];

    // preload CSR offsets for this wave's 16 nodes (+1)
    int offv = (lane < 17) ? off[tb + rowB + lane] : 0;

    // phase A: pull-reduce h_attn, batched 8-wide
    for (int i = 0; i < 16; ++i) {
        const int b0 = __shfl(offv, i), b1 = __shfl(offv, i + 1);
        float a0 = 0.f, a1 = 0.f, zz = 0.f;
        for (int j0 = b0; j0 < b1; j0 += 8) {
            int jj = j0 + (lane & 7);
            int ci = (jj < b1) ? csr_src[jj] : 0;
            unsigned vv[8]; float sv[8];
#pragma unroll
            for (int k = 0; k < 8; ++k) {
                bool ok = (j0 + k) < b1;
                int cs = __shfl(ci, k);
                vv[k] = ok ? *(const unsigned*)(Vb + (size_t)cs * 128 + 2 * lane)
                           : 0u;
                sv[k] = ok ? sexpS[(size_t)(j0 + k) * 8 + head] : 0.f;
            }
#pragma unroll
            for (int k = 0; k < 8; ++k) {
                a0 += bf2f((unsigned short)vv[k]) * sv[k];
                a1 += bf2f((unsigned short)(vv[k] >> 16)) * sv[k];
                zz += sv[k];
            }
        }
        float iz = 1.f / (zz + 1e-6f);
        *(unsigned*)(sA + (rowB + i) * 136 + 2 * lane) = packbf2(a0 * iz, a1 * iz);
    }

    __syncthreads();     // sW(WOh) staged + all sA writes visible

    f32x4 x1v[8];
    proj_ln(sA, hres, sW, bOh, g1h, b1h, rowB, c, g, lane, x1v);
    ffn_lnS(sA, sW, Wh1t, bh1, Wh2t, bh2, g2h, b2h,
            rowB, c, g, lane, tid, x1v, h2out, tb);
}

// ---------------------------------------------------------------- launch
extern "C" void kernel_launch(void* const* d_in, const int* in_sizes, int n_in,
                              void* d_out, int out_size, void* d_ws,
                              size_t ws_size, hipStream_t stream) {
    const float* h   = (const float*)d_in[0];
    const float* e   = (const float*)d_in[1];
    const int*   src = (const int*)d_in[2];
    const int*   dst = (const int*)d_in[3];
    const float* WQ  = (const float*)d_in[4];
    const float* WK  = (const float*)d_in[5];
    const float* WV  = (const float*)d_in[6];
    const float* We  = (const float*)d_in[7];
    const float* WOh = (const float*)d_in[8];
    const float* bOh = (const float*)d_in[9];
    const float* WOe = (const float*)d_in[10];
    const float* bOe = (const float*)d_in[11];
    const float* g1h = (const float*)d_in[12];
    const float* b1h = (const float*)d_in[13];
    const float* g1e = (const float*)d_in[14];
    const float* b1e = (const float*)d_in[15];
    const float* Wh1 = (const float*)d_in[16];
    const float* bh1 = (const float*)d_in[17];
    const float* Wh2 = (const float*)d_in[18];
    const float* bh2 = (const float*)d_in[19];
    const float* We1 = (const float*)d_in[20];
    const float* be1 = (const float*)d_in[21];
    const float* We2 = (const float*)d_in[22];
    const float* be2 = (const float*)d_in[23];
    const float* g2h = (const float*)d_in[24];
    const float* b2h = (const float*)d_in[25];
    const float* g2e = (const float*)d_in[26];
    const float* b2e = (const float*)d_in[27];

    unsigned short* Qb = (unsigned short*)d_ws;            // N*128 bf16
    unsigned short* Kb = Qb + (size_t)N_ * 128;
    unsigned short* Vb = Kb + (size_t)N_ * 128;
    float* sexpS = (float*)(Vb + (size_t)N_ * 128);        // E*8 (CSR slot order)
    int* cnt     = (int*)(sexpS + (size_t)E_ * 8);         // N
    int* cursor  = cnt + N_;                               // N
    int* off     = cursor + N_;                            // N+1 (pad to N+16)
    int* slotOf  = off + N_ + 16;                          // E
    int* csr_src = slotOf + E_;                            // E
    short* Wb    = (short*)(csr_src + E_);                 // bf16 weights (16B-aligned)

    float* h2out = (float*)d_out;
    float* e2out = h2out + (size_t)N_ * 128;

    prep_weights<<<896, 256, 0, stream>>>(WQ, WK, WV, We, WOh, WOe,
                                          Wh1, Wh2, We1, We2, Wb);
    hipMemsetAsync(cnt, 0, 2 * N_ * sizeof(int), stream);  // cnt + cursor
    hist_kernel<<<E_ / 256, 256, 0, stream>>>(dst, cnt);
    scan_kernel<<<1, 1024, 0, stream>>>(cnt, off);
    scatter_kernel<<<E_ / 256, 256, 0, stream>>>(src, dst, off, cursor,
                                                 slotOf, csr_src);
    qkv_kernel<<<N_ / 64, 256, 0, stream>>>(h, Wb, Qb, Kb, Vb);
    edge_kernel<<<E_ / 64, 256, 0, stream>>>(
        e, src, dst, slotOf, Qb, Kb, sexpS,
        Wb + 3 * 16384, Wb + 5 * 16384,
        Wb + 98304 + 2 * 32768, Wb + 98304 + 3 * 32768,
        bOe, g1e, b1e, be1, be2, g2e, b2e, e2out);
    node_kernel<<<N_ / 64, 256, 0, stream>>>(
        h, Vb, sexpS, off, csr_src,
        Wb + 4 * 16384, Wb + 98304, Wb + 98304 + 32768,
        bOh, g1h, b1h, bh1, bh2, g2h, b2h, h2out);
}

// Round 8
// 497.528 us; speedup vs baseline: 3.4691x; 1.0658x over previous
//
#include <hip/hip_runtime.h>
#include <hip/hip_bf16.h>

// GraphTransformerLayer on MI355X — round 8.
// vs round 7:
//  - native __float2bfloat16 casts (compiler emits v_cvt_pk_bf16_f32) instead
//    of hand-rolled 4-op RNE; ~25-30% fewer VALU ops in edge/node kernels.
//  - edge_kernel: 512 threads / 128 edges per block -> 2 blocks/CU x 8 waves
//    = 16 waves/CU (50% occupancy cap vs 37.5%), sW staging amortized 2x.

constexpr int N_ = 40000;
constexpr int E_ = 640000;

typedef __attribute__((ext_vector_type(8))) short bf16x8;
typedef __attribute__((ext_vector_type(4))) float f32x4;

__device__ inline short f2bf(float f) {
    union { __hip_bfloat16 b; short s; } u;
    u.b = __float2bfloat16(f);
    return u.s;
}
__device__ inline float bf2f(unsigned short u) {
    union { unsigned u; float f; } v; v.u = ((unsigned)u) << 16; return v.f;
}
__device__ inline unsigned packbf2(float a, float b) {
    return (unsigned)(unsigned short)f2bf(a) |
           ((unsigned)(unsigned short)f2bf(b) << 16);
}

__device__ inline f32x4 mfma16(bf16x8 a, bf16x8 b, f32x4 c) {
    return __builtin_amdgcn_mfma_f32_16x16x32_bf16(a, b, c, 0, 0, 0);
}

__device__ inline float red16(float v) {
    v += __shfl_xor(v, 1);
    v += __shfl_xor(v, 2);
    v += __shfl_xor(v, 4);
    v += __shfl_xor(v, 8);
    return v;
}

template<int KSTEPS, int LDA>
__device__ inline void load_af(const short* sA, int row, int g, bf16x8* af) {
#pragma unroll
    for (int ks = 0; ks < KSTEPS; ++ks)
        af[ks] = *(const bf16x8*)(sA + row * LDA + ks * 32 + g * 8);
}

// B-fragments from fragment-ordered LDS tile: block (n*4+ks) is 1024B,
// lane reads its own contiguous 16B slot. Conflict-free.
template<int KSTEPS>
__device__ inline f32x4 gemm_tileF(const bf16x8* af, const short* sW,
                                   int n, int lane, f32x4 acc) {
#pragma unroll
    for (int ks = 0; ks < KSTEPS; ++ks)
        acc = mfma16(af[ks],
                     *(const bf16x8*)(sW + ((n * 4 + ks) * 64 + lane) * 8), acc);
    return acc;
}

// Linear 32KB copy global(fragment-ordered) -> LDS, explicit reg staging.
// Coalesced global b128 loads, lane-contiguous ds_write_b128 (conflict-free).
template<int NT>
__device__ inline void stageWX(const short* __restrict__ Wsrc, short* sW,
                               int tid) {
    constexpr int P = 2048 / NT;
    bf16x8 tmp[P];
#pragma unroll
    for (int p = 0; p < P; ++p)
        tmp[p] = *(const bf16x8*)(Wsrc + (tid + p * NT) * 8);
#pragma unroll
    for (int p = 0; p < P; ++p)
        *(bf16x8*)(sW + (tid + p * NT) * 8) = tmp[p];
}

// Stage this wave's 16 rows of a [*,128] f32 matrix into LDS as bf16.
__device__ inline void stage64(const float* __restrict__ gsrc, short* sA,
                               int lane, int rowB) {
    int rr = rowB + (lane >> 2);
    int c0 = (lane & 3) * 32;
    const float* gp = gsrc + (size_t)rr * 128 + c0;
    short* dp = sA + rr * 136 + c0;
#pragma unroll
    for (int p = 0; p < 4; ++p) {
        float4 x = *(const float4*)(gp + p * 8);
        float4 y = *(const float4*)(gp + p * 8 + 4);
        bf16x8 v;
        v[0] = f2bf(x.x); v[1] = f2bf(x.y); v[2] = f2bf(x.z); v[3] = f2bf(x.w);
        v[4] = f2bf(y.x); v[5] = f2bf(y.y); v[6] = f2bf(y.z); v[7] = f2bf(y.w);
        *(bf16x8*)(dp + p * 8) = v;
    }
}

// x1 = LN(eres + A@W + bias); A bf16 in sA, W fragment-ordered in sW.
__device__ inline void proj_ln(short* sA, const f32x4* eres, const short* sW,
                               const float* __restrict__ bias,
                               const float* __restrict__ gma,
                               const float* __restrict__ beta,
                               int rowB, int c, int g, int lane, f32x4* x1v) {
    bf16x8 af[4];
    load_af<4, 136>(sA, rowB + c, g, af);
    float sx[4] = {0, 0, 0, 0}, sxx[4] = {0, 0, 0, 0};
#pragma unroll
    for (int n = 0; n < 8; ++n) {
        f32x4 a = gemm_tileF<4>(af, sW, n, lane, f32x4{0.f, 0.f, 0.f, 0.f});
        const int col = n * 16 + c;
        float bo = bias[col];
#pragma unroll
        for (int r = 0; r < 4; ++r) {
            float xv = a[r] + bo + eres[n][r];
            a[r] = xv; sx[r] += xv; sxx[r] += xv * xv;
        }
        x1v[n] = a;
    }
    float mean[4], inv[4];
#pragma unroll
    for (int r = 0; r < 4; ++r) {
        float s = red16(sx[r]), s2 = red16(sxx[r]);
        mean[r] = s * 0.0078125f;
        float var = s2 * 0.0078125f - mean[r] * mean[r];
        inv[r] = rsqrtf(var + 1e-5f);
    }
#pragma unroll
    for (int n = 0; n < 8; ++n) {
        const int col = n * 16 + c;
        float gg = gma[col], bb = beta[col];
#pragma unroll
        for (int r = 0; r < 4; ++r) {
            float v1 = (x1v[n][r] - mean[r]) * inv[r] * gg + bb;
            x1v[n][r] = v1;
            sA[(rowB + g * 4 + r) * 136 + col] = f2bf(v1);
        }
    }
}

// out = LN(x1 + relu(x1@W1 + b1)@W2 + b2); W1/W2 staged in 32KB halves.
template<int NT>
__device__ inline void ffn_lnS(short* sA, short* sW,
                               const short* __restrict__ W1t,
                               const float* __restrict__ b1,
                               const short* __restrict__ W2t,
                               const float* __restrict__ b2,
                               const float* __restrict__ gma,
                               const float* __restrict__ beta,
                               int rowB, int c, int g, int lane, int tid,
                               f32x4* x1v, float* __restrict__ outp, int tb) {
    bf16x8 af[4];
    load_af<4, 136>(sA, rowB + c, g, af);    // x1 fragments, kept in regs
#pragma unroll
    for (int half = 0; half < 2; ++half) {
        __syncthreads();                     // prior sW consumers done
        stageWX<NT>(W1t + half * 16384, sW, tid);
        __syncthreads();
#pragma unroll
        for (int n2 = 0; n2 < 8; ++n2) {
            f32x4 a3 = gemm_tileF<4>(af, sW, n2, lane,
                                     f32x4{0.f, 0.f, 0.f, 0.f});
            const int col2 = half * 128 + n2 * 16 + c;
            float bb = b1[col2];
#pragma unroll
            for (int r = 0; r < 4; ++r)
                sA[(rowB + g * 4 + r) * 136 + n2 * 16 + c] =
                    f2bf(fmaxf(a3[r] + bb, 0.f));
        }
        bf16x8 a4[4];
        load_af<4, 136>(sA, rowB + c, g, a4);   // u half (wave-private rows)
        __syncthreads();
        stageWX<NT>(W2t + half * 16384, sW, tid);
        __syncthreads();
#pragma unroll
        for (int n = 0; n < 8; ++n)
            x1v[n] = gemm_tileF<4>(a4, sW, n, lane, x1v[n]);
    }
    float ty[4] = {0, 0, 0, 0}, tyy[4] = {0, 0, 0, 0};
#pragma unroll
    for (int n = 0; n < 8; ++n) {
        const int col = n * 16 + c;
        float bb = b2[col];
#pragma unroll
        for (int r = 0; r < 4; ++r) {
            float xv = x1v[n][r] + bb;
            x1v[n][r] = xv; ty[r] += xv; tyy[r] += xv * xv;
        }
    }
    float mean[4], inv[4];
#pragma unroll
    for (int r = 0; r < 4; ++r) {
        float s = red16(ty[r]), s2 = red16(tyy[r]);
        mean[r] = s * 0.0078125f;
        float var = s2 * 0.0078125f - mean[r] * mean[r];
        inv[r] = rsqrtf(var + 1e-5f);
    }
#pragma unroll
    for (int n = 0; n < 8; ++n) {
        const int col = n * 16 + c;
        float gg = gma[col], bb = beta[col];
#pragma unroll
        for (int r = 0; r < 4; ++r)
            outp[(size_t)(tb + rowB + g * 4 + r) * 128 + col] =
                (x1v[n][r] - mean[r]) * inv[r] * gg + bb;
    }
}

// ---------------------------------------------------------------- prep
// Emit weights in MFMA fragment order (see gemm_tileF).
__global__ void prep_weights(
    const float* __restrict__ WQ, const float* __restrict__ WK,
    const float* __restrict__ WV, const float* __restrict__ We,
    const float* __restrict__ WOh, const float* __restrict__ WOe,
    const float* __restrict__ Wh1, const float* __restrict__ Wh2,
    const float* __restrict__ We1, const float* __restrict__ We2,
    short* __restrict__ out) {
    int i = blockIdx.x * 256 + threadIdx.x;
    if (i < 98304) {
        int m = i >> 14, r = i & 16383;
        const float* W = m == 0 ? WQ : m == 1 ? WK : m == 2 ? WV
                        : m == 3 ? We : m == 4 ? WOh : WOe;
        int blk = r >> 9, l = (r >> 3) & 63, j = r & 7;
        int n = blk >> 2, ks = blk & 3;
        int col = n * 16 + (l & 15);
        int k = ks * 32 + (l >> 4) * 8 + j;
        out[i] = f2bf(W[k * 128 + col]);
    } else if (i < 229376) {
        int j2 = i - 98304;
        int m = j2 >> 15, r = j2 & 32767;
        int half = r >> 14, q = r & 16383;
        int blk = q >> 9, l = (q >> 3) & 63, j = q & 7;
        int n = blk >> 2, ks = blk & 3;
        if (m == 0 || m == 2) {                    // W1-type [128][256]
            const float* W = (m == 0) ? Wh1 : We1;
            int col2 = half * 128 + n * 16 + (l & 15);
            int k = ks * 32 + (l >> 4) * 8 + j;
            out[i] = f2bf(W[k * 256 + col2]);
        } else {                                   // W2-type [256][128]
            const float* W = (m == 1) ? Wh2 : We2;
            int col = n * 16 + (l & 15);
            int k = half * 128 + ks * 32 + (l >> 4) * 8 + j;
            out[i] = f2bf(W[k * 128 + col]);
        }
    }
}

// ---------------------------------------------------------------- CSR build
__global__ void hist_kernel(const int* __restrict__ dst, int* __restrict__ cnt) {
    int i = blockIdx.x * 256 + threadIdx.x;
    if (i < E_) atomicAdd(&cnt[dst[i]], 1);
}

__global__ void __launch_bounds__(1024) scan_kernel(const int* __restrict__ cnt,
                                                    int* __restrict__ off) {
    __shared__ int part[1024];
    int t = threadIdx.x;
    int base = t * 40;
    int s = 0;
    if (base < N_) {
        int end = min(base + 40, N_);
        for (int i = base; i < end; ++i) s += cnt[i];
    }
    part[t] = s;
    __syncthreads();
    for (int d = 1; d < 1024; d <<= 1) {
        int v = (t >= d) ? part[t - d] : 0;
        __syncthreads();
        part[t] += v;
        __syncthreads();
    }
    int prefix = (t == 0) ? 0 : part[t - 1];
    if (base < N_) {
        int end = min(base + 40, N_);
        int run = prefix;
        for (int i = base; i < end; ++i) { off[i] = run; run += cnt[i]; }
    }
    if (t == 1023) off[N_] = part[1023];
}

__global__ void scatter_kernel(const int* __restrict__ src,
                               const int* __restrict__ dst,
                               const int* __restrict__ off,
                               int* __restrict__ cursor,
                               int* __restrict__ slotOf,
                               int* __restrict__ csr_src) {
    int i = blockIdx.x * 256 + threadIdx.x;
    if (i < E_) {
        int d = dst[i];
        int s = off[d] + atomicAdd(&cursor[d], 1);
        slotOf[i] = s;
        csr_src[s] = src[i];
    }
}

// ---------------------------------------------------------------- QKV (bf16 out)
__global__ void __launch_bounds__(256) qkv_kernel(
    const float* __restrict__ hsrc, const short* __restrict__ Wt3,
    unsigned short* __restrict__ Qo, unsigned short* __restrict__ Ko,
    unsigned short* __restrict__ Vo) {
    __shared__ __align__(16) short sA[64 * 136];
    __shared__ __align__(16) short sW[128 * 128];
    const int tid = threadIdx.x;
    const int tb = blockIdx.x * 64;
    const int lane = tid & 63, wave = tid >> 6;
    const int c = lane & 15, g = lane >> 4;
    const int rowB = wave * 16;

    stage64(hsrc + (size_t)tb * 128, sA, lane, rowB);
    bf16x8 af[4];
    load_af<4, 136>(sA, rowB + c, g, af);

    unsigned short* outs[3] = {Qo, Ko, Vo};
#pragma unroll
    for (int w = 0; w < 3; ++w) {
        __syncthreads();
        stageWX<256>(Wt3 + w * 16384, sW, tid);
        __syncthreads();
        unsigned short* op = outs[w];
#pragma unroll
        for (int n = 0; n < 8; ++n) {
            f32x4 a = gemm_tileF<4>(af, sW, n, lane, f32x4{0.f, 0.f, 0.f, 0.f});
            const int col = n * 16 + c;
#pragma unroll
            for (int r = 0; r < 4; ++r)
                op[(size_t)(tb + rowB + g * 4 + r) * 128 + col] =
                    (unsigned short)f2bf(a[r]);
        }
    }
}

// ---------------------------------------------------------------- edges
// 512 threads, 128 edges/block: 8 waves x 16 wave-private rows.
__global__ void __launch_bounds__(512) edge_kernel(
    const float* __restrict__ e, const int* __restrict__ src,
    const int* __restrict__ dst, const int* __restrict__ slotOf,
    const unsigned short* __restrict__ Qb, const unsigned short* __restrict__ Kb,
    float* __restrict__ sexpS,
    const short* __restrict__ Wet, const short* __restrict__ WOet,
    const short* __restrict__ We1t, const short* __restrict__ We2t,
    const float* __restrict__ bOe,
    const float* __restrict__ g1e, const float* __restrict__ b1e,
    const float* __restrict__ be1, const float* __restrict__ be2,
    const float* __restrict__ g2e, const float* __restrict__ b2e,
    float* __restrict__ e2out) {
    __shared__ __align__(16) short sA[128 * 136];  // e -> pe -> score -> x1 -> u
    __shared__ __align__(16) short sW[128 * 128];  // per-phase weight tile
    const int tid = threadIdx.x;
    const int tb = blockIdx.x * 128;
    const int lane = tid & 63, wave = tid >> 6;
    const int c = lane & 15, g = lane >> 4;
    const int rowB = wave * 16;

    stageWX<512>(Wet, sW, tid);
    stage64(e + (size_t)tb * 128, sA, lane, rowB);

    // preload this wave's 16 src / 16 dst / 16 slot indices (lane-partitioned)
    int pre = 0;
    {
        int li = lane & 15;
        if (lane < 16)       pre = src[tb + rowB + li];
        else if (lane < 32)  pre = dst[tb + rowB + li];
        else if (lane < 48)  pre = slotOf[tb + rowB + li];
    }

    // residual e in registers (acc layout), issued early
    f32x4 eres[8];
#pragma unroll
    for (int n = 0; n < 8; ++n)
#pragma unroll
        for (int r = 0; r < 4; ++r)
            eres[n][r] = e[(size_t)(tb + rowB + g * 4 + r) * 128 + n * 16 + c];

    __syncthreads();     // sW(We) staged

    // GEMM1: pe = e @ We -> stash bf16 into sA (wave-private rows)
    bf16x8 af[4];
    load_af<4, 136>(sA, rowB + c, g, af);
#pragma unroll
    for (int n = 0; n < 8; ++n) {
        f32x4 p = gemm_tileF<4>(af, sW, n, lane, f32x4{0.f, 0.f, 0.f, 0.f});
#pragma unroll
        for (int r = 0; r < 4; ++r)
            sA[(rowB + g * 4 + r) * 136 + n * 16 + c] = f2bf(p[r]);
    }

    // ---- score phase: 2 batches of 8 edges; gathers issued 16-deep
    const int head = lane >> 3;
#pragma unroll
    for (int b = 0; b < 2; ++b) {
        unsigned kreg[8], qreg[8];
#pragma unroll
        for (int k = 0; k < 8; ++k) {
            int sI = __shfl(pre, b * 8 + k);
            kreg[k] = *(const unsigned*)(Kb + (size_t)sI * 128 + 2 * lane);
        }
#pragma unroll
        for (int k = 0; k < 8; ++k) {
            int dI = __shfl(pre, 16 + b * 8 + k);
            qreg[k] = *(const unsigned*)(Qb + (size_t)dI * 128 + 2 * lane);
        }
#pragma unroll
        for (int k = 0; k < 8; ++k) {
            const int i = b * 8 + k;
            const int row = rowB + i;
            const int slot = __shfl(pre, 32 + i);   // full-exec shfl
            unsigned pp = *(const unsigned*)(sA + row * 136 + 2 * lane);
            float sc0 = bf2f((unsigned short)kreg[k]) *
                        bf2f((unsigned short)qreg[k]) * 0.25f *
                        bf2f((unsigned short)pp);
            float sc1 = bf2f((unsigned short)(kreg[k] >> 16)) *
                        bf2f((unsigned short)(qreg[k] >> 16)) * 0.25f *
                        bf2f((unsigned short)(pp >> 16));
            *(unsigned*)(sA + row * 136 + 2 * lane) = packbf2(sc0, sc1);
            float s = sc0 + sc1;
            s += __shfl_xor(s, 1);
            s += __shfl_xor(s, 2);
            s += __shfl_xor(s, 4);
            s = fminf(5.f, fmaxf(-5.f, s));
            if ((lane & 7) == 0)
                sexpS[(size_t)slot * 8 + head] = __expf(s);
        }
    }

    __syncthreads();     // all waves done with sW(We)
    stageWX<512>(WOet, sW, tid);
    __syncthreads();

    f32x4 x1v[8];
    proj_ln(sA, eres, sW, bOe, g1e, b1e, rowB, c, g, lane, x1v);
    ffn_lnS<512>(sA, sW, We1t, be1, We2t, be2, g2e, b2e,
                 rowB, c, g, lane, tid, x1v, e2out, tb);
}

// ---------------------------------------------------------------- nodes
__global__ void __launch_bounds__(256) node_kernel(
    const float* __restrict__ h, const unsigned short* __restrict__ Vb,
    const float* __restrict__ sexpS,
    const int* __restrict__ off, const int* __restrict__ csr_src,
    const short* __restrict__ WOht, const short* __restrict__ Wh1t,
    const short* __restrict__ Wh2t,
    const float* __restrict__ bOh,
    const float* __restrict__ g1h, const float* __restrict__ b1h,
    const float* __restrict__ bh1, const float* __restrict__ bh2,
    const float* __restrict__ g2h, const float* __restrict__ b2h,
    float* __restrict__ h2out) {
    __shared__ __align__(16) short sA[64 * 136];
    __shared__ __align__(16) short sW[128 * 128];
    const int tid = threadIdx.x;
    const int tb = blockIdx.x * 64;
    const int lane = tid & 63, wave = tid >> 6;
    const int c = lane & 15, g = lane >> 4;
    const int rowB = wave * 16;
    const int head = lane >> 3;

    stageWX<256>(WOht, sW, tid);     // overlapped with the pull phase

    // residual h in registers (acc layout)
    f32x4 hres[8];
#pragma unroll
    for (int n = 0; n < 8; ++n)
#pragma unroll
        for (int r = 0; r < 4; ++r)
            hres[n][r] = h[(size_t)(tb + rowB + g * 4 + r) * 128 + n * 16 + c];

    // preload CSR offsets for this wave's 16 nodes (+1)
    int offv = (lane < 17) ? off[tb + rowB + lane] : 0;

    // phase A: pull-reduce h_attn, batched 8-wide
    for (int i = 0; i < 16; ++i) {
        const int b0 = __shfl(offv, i), b1 = __shfl(offv, i + 1);
        float a0 = 0.f, a1 = 0.f, zz = 0.f;
        for (int j0 = b0; j0 < b1; j0 += 8) {
            int jj = j0 + (lane & 7);
            int ci = (jj < b1) ? csr_src[jj] : 0;
            unsigned vv[8]; float sv[8];
#pragma unroll
            for (int k = 0; k < 8; ++k) {
                bool ok = (j0 + k) < b1;
                int cs = __shfl(ci, k);
                vv[k] = ok ? *(const unsigned*)(Vb + (size_t)cs * 128 + 2 * lane)
                           : 0u;
                sv[k] = ok ? sexpS[(size_t)(j0 + k) * 8 + head] : 0.f;
            }
#pragma unroll
            for (int k = 0; k < 8; ++k) {
                a0 += bf2f((unsigned short)vv[k]) * sv[k];
                a1 += bf2f((unsigned short)(vv[k] >> 16)) * sv[k];
                zz += sv[k];
            }
        }
        float iz = 1.f / (zz + 1e-6f);
        *(unsigned*)(sA + (rowB + i) * 136 + 2 * lane) = packbf2(a0 * iz, a1 * iz);
    }

    __syncthreads();     // sW(WOh) staged + all sA writes visible

    f32x4 x1v[8];
    proj_ln(sA, hres, sW, bOh, g1h, b1h, rowB, c, g, lane, x1v);
    ffn_lnS<256>(sA, sW, Wh1t, bh1, Wh2t, bh2, g2h, b2h,
                 rowB, c, g, lane, tid, x1v, h2out, tb);
}

// ---------------------------------------------------------------- launch
extern "C" void kernel_launch(void* const* d_in, const int* in_sizes, int n_in,
                              void* d_out, int out_size, void* d_ws,
                              size_t ws_size, hipStream_t stream) {
    const float* h   = (const float*)d_in[0];
    const float* e   = (const float*)d_in[1];
    const int*   src = (const int*)d_in[2];
    const int*   dst = (const int*)d_in[3];
    const float* WQ  = (const float*)d_in[4];
    const float* WK  = (const float*)d_in[5];
    const float* WV  = (const float*)d_in[6];
    const float* We  = (const float*)d_in[7];
    const float* WOh = (const float*)d_in[8];
    const float* bOh = (const float*)d_in[9];
    const float* WOe = (const float*)d_in[10];
    const float* bOe = (const float*)d_in[11];
    const float* g1h = (const float*)d_in[12];
    const float* b1h = (const float*)d_in[13];
    const float* g1e = (const float*)d_in[14];
    const float* b1e = (const float*)d_in[15];
    const float* Wh1 = (const float*)d_in[16];
    const float* bh1 = (const float*)d_in[17];
    const float* Wh2 = (const float*)d_in[18];
    const float* bh2 = (const float*)d_in[19];
    const float* We1 = (const float*)d_in[20];
    const float* be1 = (const float*)d_in[21];
    const float* We2 = (const float*)d_in[22];
    const float* be2 = (const float*)d_in[23];
    const float* g2h = (const float*)d_in[24];
    const float* b2h = (const float*)d_in[25];
    const float* g2e = (const float*)d_in[26];
    const float* b2e = (const float*)d_in[27];

    unsigned short* Qb = (unsigned short*)d_ws;            // N*128 bf16
    unsigned short* Kb = Qb + (size_t)N_ * 128;
    unsigned short* Vb = Kb + (size_t)N_ * 128;
    float* sexpS = (float*)(Vb + (size_t)N_ * 128);        // E*8 (CSR slot order)
    int* cnt     = (int*)(sexpS + (size_t)E_ * 8);         // N
    int* cursor  = cnt + N_;                               // N
    int* off     = cursor + N_;                            // N+1 (pad to N+16)
    int* slotOf  = off + N_ + 16;                          // E
    int* csr_src = slotOf + E_;                            // E
    short* Wb    = (short*)(csr_src + E_);                 // bf16 weights (16B-aligned)

    float* h2out = (float*)d_out;
    float* e2out = h2out + (size_t)N_ * 128;

    prep_weights<<<896, 256, 0, stream>>>(WQ, WK, WV, We, WOh, WOe,
                                          Wh1, Wh2, We1, We2, Wb);
    hipMemsetAsync(cnt, 0, 2 * N_ * sizeof(int), stream);  // cnt + cursor
    hist_kernel<<<E_ / 256, 256, 0, stream>>>(dst, cnt);
    scan_kernel<<<1, 1024, 0, stream>>>(cnt, off);
    scatter_kernel<<<E_ / 256, 256, 0, stream>>>(src, dst, off, cursor,
                                                 slotOf, csr_src);
    qkv_kernel<<<N_ / 64, 256, 0, stream>>>(h, Wb, Qb, Kb, Vb);
    edge_kernel<<<E_ / 128, 512, 0, stream>>>(
        e, src, dst, slotOf, Qb, Kb, sexpS,
        Wb + 3 * 16384, Wb + 5 * 16384,
        Wb + 98304 + 2 * 32768, Wb + 98304 + 3 * 32768,
        bOe, g1e, b1e, be1, be2, g2e, b2e, e2out);
    node_kernel<<<N_ / 64, 256, 0, stream>>>(
        h, Vb, sexpS, off, csr_src,
        Wb + 4 * 16384, Wb + 98304, Wb + 98304 + 32768,
        bOh, g1h, b1h, bh1, bh2, g2h, b2h, h2out);
}